// Round 10
// baseline (466.428 us; speedup 1.0000x reference)
//
#include <hip/hip_runtime.h>
#include <hip/hip_bf16.h>
#include <math.h>

#define D_MODEL 1024
#define D_STATE 16
#define D_CONV 4
#define D_INNER 2048
#define DT_RANK 64
#define BATCH 4
#define SEQ 2048
#define ML (BATCH * SEQ)  // 8192 rows
#define NCH 64            // scan chunks per sequence
#define LOG_NCH 6
#define CL (SEQ / NCH)    // 32 steps per chunk

typedef __attribute__((ext_vector_type(8))) short short8;
typedef __attribute__((ext_vector_type(8))) unsigned short u16x8;
typedef __attribute__((ext_vector_type(4))) float f32x4;

// ---------------------------------------------------------------------------
// dtype helpers: inputs may be fp32 (expected) or bf16 (runtime-detected).
// ---------------------------------------------------------------------------
__device__ __forceinline__ float bf2f(unsigned short u) {
  union { unsigned int i; float f; } v;
  v.i = ((unsigned int)u) << 16;
  return v.f;
}
__device__ __forceinline__ unsigned short f2bf(float f) {
  union { float f; unsigned int i; } u;
  u.f = f;
  unsigned int r = u.i + 0x7fffu + ((u.i >> 16) & 1u);  // RNE
  return (unsigned short)(r >> 16);
}
// packed f32x2 -> bf16x2 (v_cvt_pk_bf16_f32 on gfx950); low 16 = a, high = b
__device__ __forceinline__ unsigned int f2bf_pk(float a, float b) {
  union { __hip_bfloat162 h; unsigned int u; } cv;
  cv.h = __float22bfloat162_rn(make_float2(a, b));
  return cv.u;
}
template <bool BF>
__device__ __forceinline__ float ld1(const void* p, size_t i) {
  if constexpr (BF) return bf2f(((const unsigned short*)p)[i]);
  else return ((const float*)p)[i];
}
template <bool BF>
__device__ __forceinline__ void ld4(const void* p, size_t i, float o[4]) {
  if constexpr (BF) {
    ushort4 v = *(const ushort4*)((const unsigned short*)p + i);
    o[0] = bf2f(v.x); o[1] = bf2f(v.y); o[2] = bf2f(v.z); o[3] = bf2f(v.w);
  } else {
    float4 v = *(const float4*)((const float*)p + i);
    o[0] = v.x; o[1] = v.y; o[2] = v.z; o[3] = v.w;
  }
}

// async global->LDS, 16 B per lane; lds base must be wave-uniform.
__device__ __forceinline__ void gl_lds16(const unsigned short* g,
                                         unsigned short* l) {
  __builtin_amdgcn_global_load_lds(
      (const __attribute__((address_space(1))) void*)g,
      (__attribute__((address_space(3))) void*)l, 16, 0, 0);
}

// ---------------------------------------------------------------------------
// Fused conversion of all weights/x to bf16 (one dispatch). Dtype detection
// (flag=1 means bf16 inputs) folded in; block 0 publishes flag[0].
// ---------------------------------------------------------------------------
#define CVT_N0 (ML * 1024)
#define CVT_N1 (4096 * 1024)
#define CVT_N2 (1024 * 2048)
#define CVT_N3 (2048 * 64)
#define CVT_N4 (128 * 2048)
#define CVT_E0 CVT_N0
#define CVT_E1 (CVT_E0 + CVT_N1)
#define CVT_E2 (CVT_E1 + CVT_N2)
#define CVT_E3 (CVT_E2 + CVT_N3)
#define CVT_E4 (CVT_E3 + CVT_N4)

__device__ __forceinline__ void cvt4(const void* in, size_t i,
                                     unsigned short* out, size_t o, int bf) {
  if (bf) {
    *(ushort4*)(out + o) = *(const ushort4*)((const unsigned short*)in + i);
  } else {
    float4 f = *(const float4*)((const float*)in + i);
    uint2 v;
    v.x = f2bf_pk(f.x, f.y);
    v.y = f2bf_pk(f.z, f.w);
    *(uint2*)(out + o) = v;
  }
}

__global__ __launch_bounds__(256) void cvt_all_kernel(
    const void* __restrict__ x, const void* __restrict__ ipw,
    const void* __restrict__ opw, const void* __restrict__ dtw,
    const void* __restrict__ xpw, unsigned short* __restrict__ x_bf,
    unsigned short* __restrict__ ipw_bf, unsigned short* __restrict__ opw_bf,
    unsigned short* __restrict__ dtw_bf, unsigned short* __restrict__ xpw_pad,
    int* __restrict__ flag) {
  // inline dtype sniff (same logic as the old detect_kernel)
  __shared__ int cnt;
  if (threadIdx.x == 0) cnt = 0;
  __syncthreads();
  {
    const unsigned int wv = ((const unsigned int*)x)[threadIdx.x];
    const unsigned int e = (wv >> 7) & 0xffu;
    if (e < 100u || e > 145u) atomicAdd(&cnt, 1);
  }
  __syncthreads();
  const int bf = (cnt < 32) ? 1 : 0;
  if (blockIdx.x == 0 && threadIdx.x == 0) flag[0] = bf;

  const size_t g = (size_t)(blockIdx.x * 256 + threadIdx.x) * 4;
  if (g < CVT_E0) {
    cvt4(x, g, x_bf, g, bf);
  } else if (g < CVT_E1) {
    const size_t i = g - CVT_E0;
    cvt4(ipw, i, ipw_bf, i, bf);
  } else if (g < CVT_E2) {
    const size_t i = g - CVT_E1;
    cvt4(opw, i, opw_bf, i, bf);
  } else if (g < CVT_E3) {
    const size_t i = g - CVT_E2;
    cvt4(dtw, i, dtw_bf, i, bf);
  } else if (g < CVT_E4) {
    const size_t i = g - CVT_E3;
    const int row = (int)(i >> 11);
    if (row < 96) {
      cvt4(xpw, i, xpw_pad, i, bf);
    } else {
      ushort4 z = {0, 0, 0, 0};
      *(ushort4*)(xpw_pad + i) = z;
    }
  }
}

// ---------------------------------------------------------------------------
// K1 GEMM, 256x256 8-phase schedule (T1+T2+T3+T4+T5, m201 template):
//   C[8192,4096] bf16 = A[8192,1024] * B[4096,1024]^T, all bf16.
// R2 result: 82.6 us, 834 TF, bank-conflict 0. Left untouched.
// ---------------------------------------------------------------------------
#define K1_LDA 1024
#define K1_NT 16  // K/64

#define K1_STG(srcbase, lds, t_, h_)                                       \
  {                                                                        \
    const unsigned short* s_ =                                             \
        (srcbase) + (size_t)(h_) * (128 * K1_LDA) + (size_t)(t_) * 64;     \
    unsigned short* d_ = (lds) + (((t_) & 1) * 2 + (h_)) * 8192 + w * 512; \
    gl_lds16(s_, d_);                                                      \
    gl_lds16(s_ + 64 * K1_LDA, d_ + 4096);                                 \
  }

__global__ __launch_bounds__(512, 2) void gemm256_k1(
    const unsigned short* __restrict__ A,  // 8192 x 1024 bf16
    const unsigned short* __restrict__ B,  // 4096 x 1024 bf16 (row = n)
    unsigned short* __restrict__ C) {      // 8192 x 4096 bf16
  __shared__ unsigned short As[32768];  // [buf][half][128][64]
  __shared__ unsigned short Bs[32768];
  const int tid = threadIdx.x;
  const int l = tid & 63, w = tid >> 6;
  // XCD-bijective swizzle: 512 wgs, 8 XCDs, 64 contiguous per XCD.
  const int bid = blockIdx.x;
  const int swz = (bid & 7) * 64 + (bid >> 3);
  const int m0 = (swz >> 4) * 256, n0 = (swz & 15) * 256;
  // staging per-lane source (pre-swizzled chunk; low3(row) invariant under
  // +64/+128 row offsets, so one chunk index serves all halves/calls)
  const int row0 = tid >> 3;  // 0..63 within a stage call
  const int c0 = (tid & 7) ^ (row0 & 7);
  const unsigned short* aSrc = A + (size_t)(m0 + row0) * K1_LDA + c0 * 8;
  const unsigned short* bSrc = B + (size_t)(n0 + row0) * K1_LDA + c0 * 8;
  // fragment coords
  const int q = l >> 4, mr = l & 15;
  const int wm = w >> 2, wn = w & 3;

  // prologue: tile0 (4 halves) then tile1 {B.h0,B.h1,A.h0}; wait so tile0's
  // 8 loads (the oldest) are landed, 3 half-tiles outstanding.
  K1_STG(aSrc, As, 0, 0);
  K1_STG(aSrc, As, 0, 1);
  K1_STG(bSrc, Bs, 0, 0);
  K1_STG(bSrc, Bs, 0, 1);
  K1_STG(bSrc, Bs, 1, 0);
  K1_STG(bSrc, Bs, 1, 1);
  K1_STG(aSrc, As, 1, 0);
  asm volatile("s_waitcnt vmcnt(6)" ::: "memory");
  asm volatile("s_barrier" ::: "memory");

  f32x4 acc[8][4] = {};
  for (int t = 0; t < K1_NT; ++t) {
    const int tb = (t & 1) * 2;
    // ---- P1 ds_reads: all B frags (8) + A frags mi{0,1} (4) = 12 reads
    short8 bfr[4][2];
#pragma unroll
    for (int ni = 0; ni < 4; ++ni)
#pragma unroll
      for (int kk = 0; kk < 2; ++kk) {
        const int r = (wn & 1) * 64 + ni * 16 + mr;
        const int c = kk * 4 + q;
        bfr[ni][kk] = *(const short8*)&Bs[(tb + (wn >> 1)) * 8192 + r * 64 +
                                          ((c ^ (r & 7)) * 8)];
      }
#pragma unroll
    for (int p = 0; p < 4; ++p) {
      short8 af[2][2];
#pragma unroll
      for (int i = 0; i < 2; ++i)
#pragma unroll
        for (int kk = 0; kk < 2; ++kk) {
          const int r = (2 * p + i) * 16 + mr;
          const int c = kk * 4 + q;
          af[i][kk] = *(const short8*)&As[(tb + wm) * 8192 + r * 64 +
                                          ((c ^ (r & 7)) * 8)];
        }
      // stage one half-tile (issued after this phase's ds_reads)
      if (p == 0) {
        if (t + 1 < K1_NT) K1_STG(aSrc, As, t + 1, 1);
      } else if (p == 1) {
        if (t + 2 < K1_NT) K1_STG(bSrc, Bs, t + 2, 0);
      } else if (p == 2) {
        if (t + 2 < K1_NT) K1_STG(bSrc, Bs, t + 2, 1);
      } else {
        if (t + 2 < K1_NT) K1_STG(aSrc, As, t + 2, 0);
      }
      asm volatile("s_barrier" ::: "memory");
      __builtin_amdgcn_s_setprio(1);
#pragma unroll
      for (int i = 0; i < 2; ++i)
#pragma unroll
        for (int ni = 0; ni < 4; ++ni)
#pragma unroll
          for (int kk = 0; kk < 2; ++kk)
            acc[2 * p + i][ni] = __builtin_amdgcn_mfma_f32_16x16x32_bf16(
                af[i][kk], bfr[ni][kk], acc[2 * p + i][ni], 0, 0, 0);
      __builtin_amdgcn_s_setprio(0);
      if (p == 3) {
        if (t + 2 < K1_NT) {
          asm volatile("s_waitcnt vmcnt(6)" ::: "memory");
        } else {
          asm volatile("s_waitcnt vmcnt(0)" ::: "memory");
        }
      }
      asm volatile("s_barrier" ::: "memory");
    }
  }
  // epilogue: C/D layout col=lane&15, row=(lane>>4)*4+reg  [m89/m91]
#pragma unroll
  for (int mi = 0; mi < 8; ++mi) {
#pragma unroll
    for (int ni = 0; ni < 4; ++ni) {
      const int row = m0 + wm * 128 + mi * 16 + q * 4;
      const int col = n0 + wn * 64 + ni * 16 + mr;
      const size_t off0 = (size_t)row * 4096 + col;
      const unsigned int p01 = f2bf_pk(acc[mi][ni][0], acc[mi][ni][1]);
      const unsigned int p23 = f2bf_pk(acc[mi][ni][2], acc[mi][ni][3]);
      C[off0] = (unsigned short)p01;
      C[off0 + 4096] = (unsigned short)(p01 >> 16);
      C[off0 + 2 * 4096] = (unsigned short)p23;
      C[off0 + 3 * 4096] = (unsigned short)(p23 >> 16);
    }
  }
}

// ---------------------------------------------------------------------------
// K6: out = y @ out_proj_w^T (M=8192, N=1024, K=2048), K1's schedule at
// BM=256 BN=128 BK=64. R4: verified. Untouched.
// ---------------------------------------------------------------------------
#define K6_LDA 2048
#define K6_NT 32  // K/64

#define K6_STGA(t_, h_)                                                 \
  {                                                                     \
    const unsigned short* s_ =                                          \
        aSrc + (size_t)(h_) * (128 * K6_LDA) + (size_t)(t_) * 64;       \
    unsigned short* d_ = As + (((t_) & 1) * 2 + (h_)) * 8192 + w * 512; \
    gl_lds16(s_, d_);                                                   \
    gl_lds16(s_ + 64 * K6_LDA, d_ + 4096);                              \
  }
#define K6_STGB(t_)                                            \
  {                                                            \
    const unsigned short* s_ = bSrc + (size_t)(t_) * 64;       \
    unsigned short* d_ = Bs6 + ((t_) & 1) * 8192 + w * 512;    \
    gl_lds16(s_, d_);                                          \
    gl_lds16(s_ + 64 * K6_LDA, d_ + 4096);                     \
  }

__global__ __launch_bounds__(512, 2) void gemm256x128_k6(
    const unsigned short* __restrict__ A,  // ybf 8192 x 2048 bf16
    const unsigned short* __restrict__ B,  // opw 1024 x 2048 bf16 (row = n)
    void* __restrict__ C,                  // out 8192 x 1024 (f32 or bf16)
    const int* __restrict__ flag) {
  __shared__ unsigned short As[32768];   // [buf][half][128][64]
  __shared__ unsigned short Bs6[16384];  // [buf][128][64]
  const int tid = threadIdx.x;
  const int l = tid & 63, w = tid >> 6;
  // XCD-bijective swizzle: 256 wgs, 8 XCDs, 32 contiguous per XCD.
  const int bid = blockIdx.x;
  const int swz = (bid & 7) * 32 + (bid >> 3);
  const int n0 = (swz & 7) * 128, m0 = (swz >> 3) * 256;
  const int row0 = tid >> 3;  // 0..63 within a stage call
  const int c0 = (tid & 7) ^ (row0 & 7);
  const unsigned short* aSrc = A + (size_t)(m0 + row0) * K6_LDA + c0 * 8;
  const unsigned short* bSrc = B + (size_t)(n0 + row0) * K6_LDA + c0 * 8;
  // fragment coords
  const int q = l >> 4, mr = l & 15;
  const int wm = w >> 2, wn = w & 3;

  // prologue: tile0 {A.h0,A.h1,B}, tile1 {B, A.h0}; vmcnt(4) -> tile0 landed,
  // {B(1), A.h0(1)} (4 loads) in flight.
  K6_STGA(0, 0);
  K6_STGA(0, 1);
  K6_STGB(0);
  K6_STGB(1);
  K6_STGA(1, 0);
  asm volatile("s_waitcnt vmcnt(4)" ::: "memory");
  asm volatile("s_barrier" ::: "memory");

  f32x4 acc[8][2] = {};
  for (int t = 0; t < K6_NT; ++t) {
    const int tb = (t & 1) * 2;
    // B frags for this tile (4 reads)
    short8 bfr[2][2];
#pragma unroll
    for (int ni = 0; ni < 2; ++ni)
#pragma unroll
      for (int kk = 0; kk < 2; ++kk) {
        const int r = wn * 32 + ni * 16 + mr;
        const int c = kk * 4 + q;
        bfr[ni][kk] = *(const short8*)&Bs6[(t & 1) * 8192 + r * 64 +
                                           ((c ^ (r & 7)) * 8)];
      }
#pragma unroll
    for (int p = 0; p < 4; ++p) {
      short8 af[2][2];
#pragma unroll
      for (int i = 0; i < 2; ++i)
#pragma unroll
        for (int kk = 0; kk < 2; ++kk) {
          const int r = (2 * p + i) * 16 + mr;
          const int c = kk * 4 + q;
          af[i][kk] = *(const short8*)&As[(tb + wm) * 8192 + r * 64 +
                                          ((c ^ (r & 7)) * 8)];
        }
      // stage schedule
      if (p == 0) {
        if (t + 1 < K6_NT) K6_STGA(t + 1, 1);
      } else if (p == 1) {
        if (t + 2 < K6_NT) K6_STGB(t + 2);
      } else if (p == 3) {
        if (t + 2 < K6_NT) K6_STGA(t + 2, 0);
      }
      asm volatile("s_barrier" ::: "memory");
      __builtin_amdgcn_s_setprio(1);
#pragma unroll
      for (int i = 0; i < 2; ++i)
#pragma unroll
        for (int ni = 0; ni < 2; ++ni)
#pragma unroll
          for (int kk = 0; kk < 2; ++kk)
            acc[2 * p + i][ni] = __builtin_amdgcn_mfma_f32_16x16x32_bf16(
                af[i][kk], bfr[ni][kk], acc[2 * p + i][ni], 0, 0, 0);
      __builtin_amdgcn_s_setprio(0);
      if (p == 3) {
        if (t + 2 < K6_NT) {
          asm volatile("s_waitcnt vmcnt(4)" ::: "memory");
        } else {
          asm volatile("s_waitcnt vmcnt(0)" ::: "memory");
        }
      }
      asm volatile("s_barrier" ::: "memory");
    }
  }
  // epilogue: C/D layout col=lane&15, row=(lane>>4)*4+reg  [m89/m91]
  const int bf = *flag;
#pragma unroll
  for (int mi = 0; mi < 8; ++mi) {
#pragma unroll
    for (int ni = 0; ni < 2; ++ni) {
      const int row = m0 + wm * 128 + mi * 16 + q * 4;
      const int col = n0 + wn * 32 + ni * 16 + mr;
      const size_t off0 = (size_t)row * 1024 + col;
      if (bf) {
        const unsigned int p01 = f2bf_pk(acc[mi][ni][0], acc[mi][ni][1]);
        const unsigned int p23 = f2bf_pk(acc[mi][ni][2], acc[mi][ni][3]);
        unsigned short* C16 = (unsigned short*)C;
        C16[off0] = (unsigned short)p01;
        C16[off0 + 1024] = (unsigned short)(p01 >> 16);
        C16[off0 + 2 * 1024] = (unsigned short)p23;
        C16[off0 + 3 * 1024] = (unsigned short)(p23 >> 16);
      } else {
        float* Cf = (float*)C;
#pragma unroll
        for (int j = 0; j < 4; ++j)
          Cf[off0 + (size_t)j * 1024] = acc[mi][ni][j];
      }
    }
  }
}

// ---------------------------------------------------------------------------
// K3: split-K x4 + reduce. 128x128 tile, BK=32, 4 waves, EPI3 split-K
// partials. Untouched.
// ---------------------------------------------------------------------------
template <int EPI, int TAG>
__global__ __launch_bounds__(256) void gemm_mfma(
    const unsigned short* __restrict__ Ain, int lda,
    const unsigned short* __restrict__ Bin, int ldb, void* __restrict__ C,
    int ldc, int K, const void* __restrict__ bias,
    const int* __restrict__ flag) {
  __shared__ unsigned short As[128 * 32];
  __shared__ unsigned short Bs[128 * 32];
  const unsigned short* A = Ain;
  const unsigned short* B = Bin;
  if (EPI == 3) {  // split-K slice
    A += (size_t)blockIdx.z * 512;
    B += (size_t)blockIdx.z * 512;
  }
  const int tid = threadIdx.x;
  const int l = tid & 63, w = tid >> 6;
  const int bm = blockIdx.y * 128;
  const int bn = blockIdx.x * 128;
  // staging: lane l of wave w covers row (w*16 + l/4); swizzled k-chunk.
  const int r0 = w * 16 + (l >> 2);
  const int cc = (((l & 3) ^ ((l >> 2) & 3) ^ ((l >> 4) & 3))) * 8;
  const unsigned short* Ap0 = A + (size_t)(bm + r0) * lda + cc;
  const unsigned short* Ap1 = A + (size_t)(bm + r0 + 64) * lda + cc;
  const unsigned short* Bp0 = B + (size_t)(bn + r0) * ldb + cc;
  const unsigned short* Bp1 = B + (size_t)(bn + r0 + 64) * ldb + cc;
  // fragment coords
  const int q = l >> 4, mr = l & 15;
  const int wm = w >> 1, wn = w & 1;
  const int slot = (q ^ (mr & 3) ^ (mr >> 2)) * 8;  // swizzled k-slot
  f32x4 acc[4][4] = {};
  for (int k0 = 0; k0 < K; k0 += 32) {
    gl_lds16(Ap0 + k0, As + w * 512);
    gl_lds16(Ap1 + k0, As + 2048 + w * 512);
    gl_lds16(Bp0 + k0, Bs + w * 512);
    gl_lds16(Bp1 + k0, Bs + 2048 + w * 512);
    __syncthreads();  // drains vmcnt (global_load_lds)
    short8 af[4], bfr[4];
#pragma unroll
    for (int mi = 0; mi < 4; ++mi)
      af[mi] = *(const short8*)&As[(wm * 64 + mi * 16 + mr) * 32 + slot];
#pragma unroll
    for (int ni = 0; ni < 4; ++ni)
      bfr[ni] = *(const short8*)&Bs[(wn * 64 + ni * 16 + mr) * 32 + slot];
#pragma unroll
    for (int mi = 0; mi < 4; ++mi)
#pragma unroll
      for (int ni = 0; ni < 4; ++ni)
        acc[mi][ni] = __builtin_amdgcn_mfma_f32_16x16x32_bf16(
            af[mi], bfr[ni], acc[mi][ni], 0, 0, 0);
    __syncthreads();
  }
  // epilogue: C/D layout col=lane&15, row=(lane>>4)*4+reg  [m89/m91]
  float* Cp3 = (EPI == 3)
                   ? ((float*)C + (size_t)blockIdx.z * ML * 128)
                   : (float*)C;
#pragma unroll
  for (int mi = 0; mi < 4; ++mi) {
#pragma unroll
    for (int ni = 0; ni < 4; ++ni) {
      const int row = bm + wm * 64 + mi * 16 + q * 4;
      const int col = bn + wn * 64 + ni * 16 + mr;
      const size_t off0 = (size_t)row * ldc + col;
      if (EPI == 3) {
#pragma unroll
        for (int j = 0; j < 4; ++j)
          Cp3[off0 + (size_t)j * ldc] = acc[mi][ni][j];
      } else {
        const unsigned int p01 = f2bf_pk(acc[mi][ni][0], acc[mi][ni][1]);
        const unsigned int p23 = f2bf_pk(acc[mi][ni][2], acc[mi][ni][3]);
        unsigned short* C16 = (unsigned short*)C;
        C16[off0] = (unsigned short)p01;
        C16[off0 + ldc] = (unsigned short)(p01 >> 16);
        C16[off0 + 2 * (size_t)ldc] = (unsigned short)p23;
        C16[off0 + 3 * (size_t)ldc] = (unsigned short)(p23 >> 16);
      }
    }
  }
}

// Split-K reduce: dbl = bf16(sum of 4 f32 partials). 1M elems, 4/thread.
__global__ __launch_bounds__(256) void reduceK3_kernel(
    const float* __restrict__ part, unsigned short* __restrict__ dbl) {
  const size_t i = (size_t)(blockIdx.x * 256 + threadIdx.x) * 4;
  const size_t st = (size_t)ML * 128;
  float4 a = *(const float4*)(part + i);
  float4 b = *(const float4*)(part + st + i);
  float4 c = *(const float4*)(part + 2 * st + i);
  float4 d = *(const float4*)(part + 3 * st + i);
  uint2 v;
  v.x = f2bf_pk(a.x + b.x + c.x + d.x, a.y + b.y + c.y + d.y);
  v.y = f2bf_pk(a.z + b.z + c.z + d.z, a.w + b.w + c.w + d.w);
  *(uint2*)(dbl + i) = v;
}

// ---------------------------------------------------------------------------
// K4: dt = softplus(dbl[:,0:64] @ dtw^T + b) -> xzb x-half (ldc=4096).
// Persistent-B single-shot GEMM, 256 wgs = 1/CU, 4-buffer A ring, counted
// vmcnt(4). Untouched from R3.
// ---------------------------------------------------------------------------
__global__ __launch_bounds__(256) void dt_gemm_kernel(
    const unsigned short* __restrict__ Adbl,  // (ML,128) bf16, cols 0:64 used
    const unsigned short* __restrict__ Bw,    // (2048,64) bf16
    unsigned short* __restrict__ Cdt,         // xzb base; ldc=4096, x-half
    const void* __restrict__ bias, const int* __restrict__ flag) {
  __shared__ unsigned short Bs[128 * 64];      // 16 KiB
  __shared__ unsigned short Ass[4][128 * 64];  // 64 KiB ring
  const int tid = threadIdx.x;
  const int l = tid & 63, w = tid >> 6;
  const int bn = blockIdx.x * 128;   // n-tile
  const int mg = blockIdx.y * 512;   // m-group (4 x 128 rows)
  // staging: per call, 256 thr cover 32 rows x 64 cols (128B rows);
  // pre-swizzled source chunk (row&7 invariant under +32 row offsets).
  const int srow = tid >> 3;                    // 0..31
  const int sc = ((tid & 7) ^ (srow & 7)) * 8;  // chunk involution
  const unsigned short* aSrc = Adbl + (size_t)(mg + srow) * 128 + sc;
  const unsigned short* bSrc = Bw + (size_t)(bn + srow) * 64 + sc;
#define K4_STGB(i_) gl_lds16(bSrc + (i_) * 32 * 64, Bs + (i_)*2048 + w * 512)
#define K4_STGA(mt_, i_)                                  \
  gl_lds16(aSrc + (size_t)((mt_)*128 + (i_)*32) * 128,    \
           Ass[(mt_) & 3] + (i_)*2048 + w * 512)
  // prologue: B (4), A0 (4), A1 (4) = 12 outstanding; vmcnt(4) -> B,A0 landed
  K4_STGB(0); K4_STGB(1); K4_STGB(2); K4_STGB(3);
  K4_STGA(0, 0); K4_STGA(0, 1); K4_STGA(0, 2); K4_STGA(0, 3);
  K4_STGA(1, 0); K4_STGA(1, 1); K4_STGA(1, 2); K4_STGA(1, 3);
  asm volatile("s_waitcnt vmcnt(4)" ::: "memory");
  asm volatile("s_barrier" ::: "memory");
  // fragment coords
  const int q = l >> 4, mr = l & 15;
  const int wm = w >> 1, wn = w & 1;
  // hoist B fragments (reused across all 4 m-tiles)
  short8 bfr[4][2];
#pragma unroll
  for (int ni = 0; ni < 4; ++ni)
#pragma unroll
    for (int kk = 0; kk < 2; ++kk) {
      const int r = wn * 64 + ni * 16 + mr;
      const int c = kk * 4 + q;
      bfr[ni][kk] = *(const short8*)&Bs[r * 64 + ((c ^ (r & 7)) * 8)];
    }
  // hoist bias (col fixed per ni)
  const int bf = *flag;
  float bv[4];
#pragma unroll
  for (int ni = 0; ni < 4; ++ni) {
    const int col = bn + wn * 64 + ni * 16 + mr;
    bv[ni] = bf ? ld1<true>(bias, col) : ld1<false>(bias, col);
  }
#pragma unroll
  for (int mt = 0; mt < 4; ++mt) {
    // stage A(mt+2) into ring slot (mt+2)&3 (free since iter mt-2)
    if (mt + 2 < 4) {
      K4_STGA(mt + 2, 0); K4_STGA(mt + 2, 1);
      K4_STGA(mt + 2, 2); K4_STGA(mt + 2, 3);
    }
    // A fragments of this m-tile (landed per prologue/loop ledger)
    short8 af[4][2];
#pragma unroll
    for (int mi = 0; mi < 4; ++mi)
#pragma unroll
      for (int kk = 0; kk < 2; ++kk) {
        const int r = wm * 64 + mi * 16 + mr;
        const int c = kk * 4 + q;
        af[mi][kk] =
            *(const short8*)&Ass[mt & 3][r * 64 + ((c ^ (r & 7)) * 8)];
      }
    f32x4 acc[4][4] = {};
#pragma unroll
    for (int mi = 0; mi < 4; ++mi)
#pragma unroll
      for (int ni = 0; ni < 4; ++ni)
#pragma unroll
        for (int kk = 0; kk < 2; ++kk)
          acc[mi][ni] = __builtin_amdgcn_mfma_f32_16x16x32_bf16(
              af[mi][kk], bfr[ni][kk], acc[mi][ni], 0, 0, 0);
    // epilogue: softplus + bf16 store (C/D layout m89/m91)
#pragma unroll
    for (int mi = 0; mi < 4; ++mi) {
#pragma unroll
      for (int ni = 0; ni < 4; ++ni) {
        const int row = mg + mt * 128 + wm * 64 + mi * 16 + q * 4;
        const int col = bn + wn * 64 + ni * 16 + mr;
        const size_t off0 = (size_t)row * 4096 + col;
        float v[4];
#pragma unroll
        for (int j = 0; j < 4; ++j) {
          const float t = acc[mi][ni][j] + bv[ni];
          v[j] = fmaxf(t, 0.f) + __logf(1.f + __expf(-fabsf(t)));
        }
        const unsigned int p01 = f2bf_pk(v[0], v[1]);
        const unsigned int p23 = f2bf_pk(v[2], v[3]);
        Cdt[off0] = (unsigned short)p01;
        Cdt[off0 + 4096] = (unsigned short)(p01 >> 16);
        Cdt[off0 + 2 * 4096] = (unsigned short)p23;
        Cdt[off0 + 3 * 4096] = (unsigned short)(p23 >> 16);
      }
    }
    // close ledger for next iter: A(mt+1) landed (only A(mt+2) outstanding)
    if (mt + 2 < 4) {
      asm volatile("s_waitcnt vmcnt(4)" ::: "memory");
    } else {
      asm volatile("s_waitcnt vmcnt(0)" ::: "memory");
    }
    if (mt < 3) asm volatile("s_barrier" ::: "memory");
  }
}

// ---------------------------------------------------------------------------
// Depthwise causal conv (width 4) + bias + SiLU, 4 channels per thread.
// xzb: (ML,4096) bf16; x part = cols [0,2048). Output xcb (ML,2048) bf16.
// ---------------------------------------------------------------------------
__global__ __launch_bounds__(256) void conv_silu_kernel(
    const unsigned short* __restrict__ xzb, const void* __restrict__ cw,
    const void* __restrict__ cb, unsigned short* __restrict__ xcb,
    const int* __restrict__ flag) {
  const int bf = *flag;
  const int e = (blockIdx.x * 256 + threadIdx.x) * 4;  // over ML*D_INNER
  const int d = e & (D_INNER - 1);
  const int bl = e >> 11;
  const int l = bl & (SEQ - 1);
  const size_t base = (size_t)bl * 4096 + d;
  float x0[4], x1[4] = {}, x2[4] = {}, x3[4] = {};
  ld4<true>(xzb, base, x0);
  if (l >= 1) ld4<true>(xzb, base - 4096, x1);
  if (l >= 2) ld4<true>(xzb, base - 2 * 4096, x2);
  if (l >= 3) ld4<true>(xzb, base - 3 * 4096, x3);
  float r[4];
#pragma unroll
  for (int i = 0; i < 4; ++i) {
    float w[4];
    if (bf) ld4<true>(cw, (size_t)(d + i) * 4, w);
    else ld4<false>(cw, (size_t)(d + i) * 4, w);
    const float bias = bf ? ld1<true>(cb, d + i) : ld1<false>(cb, d + i);
    float acc = bias + w[3] * x0[i] + w[2] * x1[i] + w[1] * x2[i] + w[0] * x3[i];
    r[i] = acc / (1.f + __expf(-acc));  // silu
  }
  uint2 o;
  o.x = f2bf_pk(r[0], r[1]);
  o.y = f2bf_pk(r[2], r[3]);
  *(uint2*)(xcb + e) = o;
}

// ---------------------------------------------------------------------------
// Chunked selective scan — R9: 2-way state-split. Each (b,c,d) channel is
// handled by TWO threads (lane halves): lanes 0-31 own n=0..7, lanes 32-63
// own n=8..15. Per-thread state a[8]+h[8]+pw[8] (~46 VGPR vs ~100 before)
// -> 8 waves/SIMD occupancy restored (VGPR cliff at 64, m69). passC closes
// the n-sum with one __shfl_xor(y,32). Arithmetic per n identical; only the
// final y-sum is re-associated (sub-bf16-quantization).
// S layout [b][c][n][d] (coalesced); P recomputed in passB from sdt.
// ---------------------------------------------------------------------------
__device__ __forceinline__ void load_a8(const void* A_log, int bf, int d,
                                        int half, float a[8], float& dev) {
  float t0[4], t1[4];
  const size_t off = (size_t)d * 16 + half * 8;
  if (bf) {
    ld4<true>(A_log, off, t0);
    ld4<true>(A_log, off + 4, t1);
  } else {
    ld4<false>(A_log, off, t0);
    ld4<false>(A_log, off + 4, t1);
  }
#pragma unroll
  for (int j = 0; j < 4; ++j) {
    a[j] = -expf(t0[j]);
    a[4 + j] = -expf(t1[j]);
  }
  dev = 0.f;
#pragma unroll
  for (int j = 0; j < 8; ++j)
    dev = fmaxf(dev, fabsf(a[j] + (float)(half * 8 + j + 1)));
}

// pw[j] = e1^(half*8 + j + 1): build e1..e8, scale by e8 for the high half.
__device__ __forceinline__ void pow8(float e1, int half, float pw[8]) {
  const float e2 = e1 * e1;
  const float e3 = e2 * e1;
  const float e4 = e2 * e2;
  const float e5 = e4 * e1, e6 = e4 * e2, e7 = e4 * e3, e8 = e4 * e4;
  const float s = half ? e8 : 1.0f;
  pw[0] = s * e1; pw[1] = s * e2; pw[2] = s * e3; pw[3] = s * e4;
  pw[4] = s * e5; pw[5] = s * e6; pw[6] = s * e7; pw[7] = s * e8;
}

// Pass A: from h=0, chunk-final state S[b][c][n][d]; sdt per (b,c,d).
// Grid: BATCH*NCH*(D_INNER/128) = 4096 blocks x 256 thr (2 thr/channel).
__global__ __launch_bounds__(256) void scan_passA(
    const unsigned short* __restrict__ xzb,
    const unsigned short* __restrict__ xcb,
    const unsigned short* __restrict__ dbl, const void* __restrict__ A_log,
    const int* __restrict__ flag, float* __restrict__ S,
    float* __restrict__ Sdt) {
  const int bf = *flag;
  const int blk = blockIdx.x;
  const int tid = threadIdx.x;
  const int lane = tid & 63, w = tid >> 6;
  const int half = lane >> 5, dl = lane & 31;
  const int d = ((blk & 15) << 7) + w * 32 + dl;
  const int c = (blk >> 4) & (NCH - 1);
  const int b = blk >> (4 + LOG_NCH);
  float a[8], dev;
  load_a8(A_log, bf, d, half, a, dev);
  const bool trick = dev < 1e-3f;
  float h[8] = {};
  float sdt = 0.f;
  const size_t m0 = (size_t)b * SEQ + c * CL;
  if (trick) {  // integer-decay fast path
    for (int t = 0; t < CL; ++t) {
      const size_t m = m0 + t;
      const float dtv = bf2f(xzb[m * 4096 + d]);
      const float xv = bf2f(xcb[m * 2048 + d]);
      const u16x8 Bv = *(const u16x8*)&dbl[m * 128 + 64 + half * 8];
      const float dtx = dtv * xv;
      sdt += dtv;
      float pw[8];
      pow8(__expf(-dtv), half, pw);
#pragma unroll
      for (int n = 0; n < 8; ++n)
        h[n] = fmaf(pw[n], h[n], bf2f(Bv[n]) * dtx);
    }
  } else {
    for (int t = 0; t < CL; ++t) {
      const size_t m = m0 + t;
      const float dtv = bf2f(xzb[m * 4096 + d]);
      const float xv = bf2f(xcb[m * 2048 + d]);
      const u16x8 Bv = *(const u16x8*)&dbl[m * 128 + 64 + half * 8];
      const float dtx = dtv * xv;
      sdt += dtv;
#pragma unroll
      for (int n = 0; n < 8; ++n)
        h[n] = fmaf(__expf(dtv * a[n]), h[n], bf2f(Bv[n]) * dtx);
    }
  }
  // coalesced: consecutive threads = consecutive d (per half-wave 128B/inst)
  const size_t sbase =
      (((size_t)b * NCH + c) * 16 + half * 8) * D_INNER + d;
#pragma unroll
  for (int n = 0; n < 8; ++n) S[sbase + (size_t)n * D_INNER] = h[n];
  if (!half) Sdt[((size_t)b * NCH + c) * D_INNER + d] = sdt;
}

// Pass B: serial prefix over NCH chunks; S[c] becomes the INITIAL state of
// chunk c. One thread per (b,n,d) = 131072, d-fast for coalescing.
__global__ __launch_bounds__(256) void scan_passB(
    float* __restrict__ S, const float* __restrict__ Sdt,
    const void* __restrict__ A_log, const int* __restrict__ flag) {
  const int bf = *flag;
  const int idx = blockIdx.x * 256 + threadIdx.x;
  const int d = idx & (D_INNER - 1);
  const int n = (idx >> 11) & 15;
  const int b = idx >> 15;
  const float al = bf ? ld1<true>(A_log, (size_t)d * 16 + n)
                      : ld1<false>(A_log, (size_t)d * 16 + n);
  const float a = -expf(al);
  float h = 0.f;
  for (int c = 0; c < NCH; ++c) {
    const size_t base = ((size_t)b * NCH + c);
    const size_t sidx = (base * 16 + n) * D_INNER + d;
    const float s = S[sidx];
    const float sdt = Sdt[base * D_INNER + d];
    const float p = __expf(a * sdt);
    S[sidx] = h;  // init for chunk c
    h = p * h + s;
  }
}

// Pass C: replay chunk from true init state; y = (sum_n h*C + D*x)*silu(z).
// Same 2-way split; y closed via shfl_xor(32); half 0 stores.
__global__ __launch_bounds__(256) void scan_passC(
    const unsigned short* __restrict__ xzb,
    const unsigned short* __restrict__ xcb,
    const unsigned short* __restrict__ dbl, const void* __restrict__ A_log,
    const void* __restrict__ Dp, const float* __restrict__ S,
    const int* __restrict__ flag, unsigned short* __restrict__ ybf) {
  const int bf = *flag;
  const int blk = blockIdx.x;
  const int tid = threadIdx.x;
  const int lane = tid & 63, w = tid >> 6;
  const int half = lane >> 5, dl = lane & 31;
  const int d = ((blk & 15) << 7) + w * 32 + dl;
  const int c = (blk >> 4) & (NCH - 1);
  const int b = blk >> (4 + LOG_NCH);
  float a[8], dev;
  load_a8(A_log, bf, d, half, a, dev);
  const bool trick = dev < 1e-3f;
  const float Dv = bf ? ld1<true>(Dp, d) : ld1<false>(Dp, d);
  float h[8];
  const size_t sbase =
      (((size_t)b * NCH + c) * 16 + half * 8) * D_INNER + d;
#pragma unroll
  for (int n = 0; n < 8; ++n) h[n] = S[sbase + (size_t)n * D_INNER];
  const size_t m0 = (size_t)b * SEQ + c * CL;
  for (int t = 0; t < CL; ++t) {
    const size_t m = m0 + t;
    const float dtv = bf2f(xzb[m * 4096 + d]);
    const float xv = bf2f(xcb[m * 2048 + d]);
    const u16x8 Bv = *(const u16x8*)&dbl[m * 128 + 64 + half * 8];
    const u16x8 Cv = *(const u16x8*)&dbl[m * 128 + 80 + half * 8];
    const float dtx = dtv * xv;
    float y = 0.f;
    if (trick) {
      float pw[8];
      pow8(__expf(-dtv), half, pw);
#pragma unroll
      for (int n = 0; n < 8; ++n) {
        h[n] = fmaf(pw[n], h[n], bf2f(Bv[n]) * dtx);
        y = fmaf(h[n], bf2f(Cv[n]), y);
      }
    } else {
#pragma unroll
      for (int n = 0; n < 8; ++n) {
        h[n] = fmaf(__expf(dtv * a[n]), h[n], bf2f(Bv[n]) * dtx);
        y = fmaf(h[n], bf2f(Cv[n]), y);
      }
    }
    y += __shfl_xor(y, 32);  // combine the two n-halves
    if (!half) {
      const float zv = bf2f(xzb[m * 4096 + 2048 + d]);
      const float yv = y + Dv * xv;
      ybf[m * 2048 + d] = f2bf(yv * (zv / (1.f + __expf(-zv))));
    }
  }
}

// ---------------------------------------------------------------------------
extern "C" void kernel_launch(void* const* d_in, const int* in_sizes, int n_in,
                              void* d_out, int out_size, void* d_ws,
                              size_t ws_size, hipStream_t stream) {
  const void* x = d_in[0];
  const void* in_proj_w = d_in[1];
  const void* conv_w = d_in[2];
  const void* conv_b = d_in[3];
  const void* x_proj_w = d_in[4];
  const void* dt_proj_w = d_in[5];
  const void* dt_proj_b = d_in[6];
  const void* A_log = d_in[7];
  const void* D_param = d_in[8];
  const void* out_proj_w = d_in[9];

  // ws layout:
  // flag 256B | xzb 64MB | xcb 32MB (pre-conv hosts x_bf+ipw_bf) | dbl 2MB |
  // ybf 32MB | S 33.5MB (NCH=64; aliases k3part 16.8MB pre-scan) | Sdt 2MB |
  // opw 4MB | xpw_pad 512KB | dtw 256KB
  char* wsb = (char*)d_ws;
  int* flag = (int*)wsb;
  unsigned short* xzb = (unsigned short*)(wsb + 256);
  unsigned short* xcb = xzb + (size_t)ML * 4096;
  unsigned short* dbl = xcb + (size_t)ML * 2048;
  unsigned short* ybf = dbl + (size_t)ML * 128;
  float* S = (float*)(ybf + (size_t)ML * 2048);
  float* Sdt = S + (size_t)BATCH * NCH * D_INNER * 16;
  unsigned short* opw_bf =
      (unsigned short*)(Sdt + (size_t)BATCH * NCH * D_INNER);
  unsigned short* xpw_pad = opw_bf + (size_t)1024 * 2048;
  unsigned short* dtw_bf = xpw_pad + (size_t)128 * 2048;
  unsigned short* x_bf = xcb;                        // dead after K1
  unsigned short* ipw_bf = xcb + (size_t)ML * 1024;  // dead after K1
  float* k3part = S;  // 4 x (ML x 128) f32 = 16.78 MB; dead before scans

  // fused conversions + inline dtype detection (one dispatch)
  cvt_all_kernel<<<CVT_E4 / 1024, 256, 0, stream>>>(
      x, in_proj_w, out_proj_w, dt_proj_w, x_proj_w, x_bf, ipw_bf, opw_bf,
      dtw_bf, xpw_pad, flag);
  // K1: xz = x @ in_proj_w^T (M=8192,N=4096,K=1024) -> xzb bf16
  gemm256_k1<<<dim3(512), 512, 0, stream>>>(x_bf, ipw_bf, xzb);
  // K2: causal depthwise conv + SiLU -> xcb bf16 (x_bf/ipw_bf now dead)
  conv_silu_kernel<<<(ML * D_INNER) / 1024, 256, 0, stream>>>(
      xzb, conv_w, conv_b, xcb, flag);
  // K3: dbl = xc @ x_proj_w^T (M=8192, N=128(pad), K=2048), split-K x4 ->
  // f32 partials in S region, then reduce+bf16.
  {
    dim3 g(1, ML / 128, 4);
    gemm_mfma<3, 3><<<g, 256, 0, stream>>>(xcb, 2048, xpw_pad, 2048, k3part,
                                           128, 512, nullptr, flag);
  }
  reduceK3_kernel<<<(ML * 128) / 1024, 256, 0, stream>>>(k3part, dbl);
  // K4: dt = softplus(dbl[:,:64] @ dt_proj_w^T + b) -> xzb x-half (ldc=4096)
  dt_gemm_kernel<<<dim3(16, 16), 256, 0, stream>>>(dbl, dtw_bf, xzb,
                                                   dt_proj_b, flag);
  // K5: chunked scan, NCH=64, 2-way state-split (A/C: 2 thr per channel)
  scan_passA<<<BATCH * NCH * (D_INNER / 128), 256, 0, stream>>>(
      xzb, xcb, dbl, A_log, flag, S, Sdt);
  scan_passB<<<(BATCH * D_INNER * 16) / 256, 256, 0, stream>>>(S, Sdt, A_log,
                                                               flag);
  scan_passC<<<BATCH * NCH * (D_INNER / 128), 256, 0, stream>>>(
      xzb, xcb, dbl, A_log, D_param, S, flag, ybf);
  // K6: out = y @ out_proj_w^T (M=8192,N=1024,K=2048), out dtype per flag
  gemm256x128_k6<<<dim3(256), 512, 0, stream>>>(ybf, opw_bf, d_out, flag);
}

// Round 11
// 430.505 us; speedup vs baseline: 1.0834x; 1.0834x over previous
//
#include <hip/hip_runtime.h>
#include <hip/hip_bf16.h>
#include <math.h>

#define D_MODEL 1024
#define D_STATE 16
#define D_CONV 4
#define D_INNER 2048
#define DT_RANK 64
#define BATCH 4
#define SEQ 2048
#define ML (BATCH * SEQ)  // 8192 rows
#define NCH 64            // scan chunks per sequence
#define LOG_NCH 6
#define CL (SEQ / NCH)    // 32 steps per chunk

typedef __attribute__((ext_vector_type(8))) short short8;
typedef __attribute__((ext_vector_type(8))) unsigned short u16x8;
typedef __attribute__((ext_vector_type(4))) float f32x4;

// ---------------------------------------------------------------------------
// dtype helpers: inputs may be fp32 (expected) or bf16 (runtime-detected).
// ---------------------------------------------------------------------------
__device__ __forceinline__ float bf2f(unsigned short u) {
  union { unsigned int i; float f; } v;
  v.i = ((unsigned int)u) << 16;
  return v.f;
}
__device__ __forceinline__ unsigned short f2bf(float f) {
  union { float f; unsigned int i; } u;
  u.f = f;
  unsigned int r = u.i + 0x7fffu + ((u.i >> 16) & 1u);  // RNE
  return (unsigned short)(r >> 16);
}
// packed f32x2 -> bf16x2 (v_cvt_pk_bf16_f32 on gfx950); low 16 = a, high = b
__device__ __forceinline__ unsigned int f2bf_pk(float a, float b) {
  union { __hip_bfloat162 h; unsigned int u; } cv;
  cv.h = __float22bfloat162_rn(make_float2(a, b));
  return cv.u;
}
template <bool BF>
__device__ __forceinline__ float ld1(const void* p, size_t i) {
  if constexpr (BF) return bf2f(((const unsigned short*)p)[i]);
  else return ((const float*)p)[i];
}
template <bool BF>
__device__ __forceinline__ void ld4(const void* p, size_t i, float o[4]) {
  if constexpr (BF) {
    ushort4 v = *(const ushort4*)((const unsigned short*)p + i);
    o[0] = bf2f(v.x); o[1] = bf2f(v.y); o[2] = bf2f(v.z); o[3] = bf2f(v.w);
  } else {
    float4 v = *(const float4*)((const float*)p + i);
    o[0] = v.x; o[1] = v.y; o[2] = v.z; o[3] = v.w;
  }
}

// async global->LDS, 16 B per lane; lds base must be wave-uniform.
__device__ __forceinline__ void gl_lds16(const unsigned short* g,
                                         unsigned short* l) {
  __builtin_amdgcn_global_load_lds(
      (const __attribute__((address_space(1))) void*)g,
      (__attribute__((address_space(3))) void*)l, 16, 0, 0);
}

// ---------------------------------------------------------------------------
// Fused conversion of all weights/x to bf16 (one dispatch). Dtype detection
// (flag=1 means bf16 inputs) folded in; block 0 publishes flag[0].
// ---------------------------------------------------------------------------
#define CVT_N0 (ML * 1024)
#define CVT_N1 (4096 * 1024)
#define CVT_N2 (1024 * 2048)
#define CVT_N3 (2048 * 64)
#define CVT_N4 (128 * 2048)
#define CVT_E0 CVT_N0
#define CVT_E1 (CVT_E0 + CVT_N1)
#define CVT_E2 (CVT_E1 + CVT_N2)
#define CVT_E3 (CVT_E2 + CVT_N3)
#define CVT_E4 (CVT_E3 + CVT_N4)

__device__ __forceinline__ void cvt4(const void* in, size_t i,
                                     unsigned short* out, size_t o, int bf) {
  if (bf) {
    *(ushort4*)(out + o) = *(const ushort4*)((const unsigned short*)in + i);
  } else {
    float4 f = *(const float4*)((const float*)in + i);
    uint2 v;
    v.x = f2bf_pk(f.x, f.y);
    v.y = f2bf_pk(f.z, f.w);
    *(uint2*)(out + o) = v;
  }
}

__global__ __launch_bounds__(256) void cvt_all_kernel(
    const void* __restrict__ x, const void* __restrict__ ipw,
    const void* __restrict__ opw, const void* __restrict__ dtw,
    const void* __restrict__ xpw, unsigned short* __restrict__ x_bf,
    unsigned short* __restrict__ ipw_bf, unsigned short* __restrict__ opw_bf,
    unsigned short* __restrict__ dtw_bf, unsigned short* __restrict__ xpw_pad,
    int* __restrict__ flag) {
  // inline dtype sniff (same logic as the old detect_kernel)
  __shared__ int cnt;
  if (threadIdx.x == 0) cnt = 0;
  __syncthreads();
  {
    const unsigned int wv = ((const unsigned int*)x)[threadIdx.x];
    const unsigned int e = (wv >> 7) & 0xffu;
    if (e < 100u || e > 145u) atomicAdd(&cnt, 1);
  }
  __syncthreads();
  const int bf = (cnt < 32) ? 1 : 0;
  if (blockIdx.x == 0 && threadIdx.x == 0) flag[0] = bf;

  const size_t g = (size_t)(blockIdx.x * 256 + threadIdx.x) * 4;
  if (g < CVT_E0) {
    cvt4(x, g, x_bf, g, bf);
  } else if (g < CVT_E1) {
    const size_t i = g - CVT_E0;
    cvt4(ipw, i, ipw_bf, i, bf);
  } else if (g < CVT_E2) {
    const size_t i = g - CVT_E1;
    cvt4(opw, i, opw_bf, i, bf);
  } else if (g < CVT_E3) {
    const size_t i = g - CVT_E2;
    cvt4(dtw, i, dtw_bf, i, bf);
  } else if (g < CVT_E4) {
    const size_t i = g - CVT_E3;
    const int row = (int)(i >> 11);
    if (row < 96) {
      cvt4(xpw, i, xpw_pad, i, bf);
    } else {
      ushort4 z = {0, 0, 0, 0};
      *(ushort4*)(xpw_pad + i) = z;
    }
  }
}

// ---------------------------------------------------------------------------
// K1 GEMM, 256x256 8-phase schedule (T1+T2+T3+T4+T5, m201 template):
//   C[8192,4096] bf16 = A[8192,1024] * B[4096,1024]^T, all bf16.
// R2 result: 82.6 us, 834 TF, bank-conflict 0. Left untouched.
// ---------------------------------------------------------------------------
#define K1_LDA 1024
#define K1_NT 16  // K/64

#define K1_STG(srcbase, lds, t_, h_)                                       \
  {                                                                        \
    const unsigned short* s_ =                                             \
        (srcbase) + (size_t)(h_) * (128 * K1_LDA) + (size_t)(t_) * 64;     \
    unsigned short* d_ = (lds) + (((t_) & 1) * 2 + (h_)) * 8192 + w * 512; \
    gl_lds16(s_, d_);                                                      \
    gl_lds16(s_ + 64 * K1_LDA, d_ + 4096);                                 \
  }

__global__ __launch_bounds__(512, 2) void gemm256_k1(
    const unsigned short* __restrict__ A,  // 8192 x 1024 bf16
    const unsigned short* __restrict__ B,  // 4096 x 1024 bf16 (row = n)
    unsigned short* __restrict__ C) {      // 8192 x 4096 bf16
  __shared__ unsigned short As[32768];  // [buf][half][128][64]
  __shared__ unsigned short Bs[32768];
  const int tid = threadIdx.x;
  const int l = tid & 63, w = tid >> 6;
  // XCD-bijective swizzle: 512 wgs, 8 XCDs, 64 contiguous per XCD.
  const int bid = blockIdx.x;
  const int swz = (bid & 7) * 64 + (bid >> 3);
  const int m0 = (swz >> 4) * 256, n0 = (swz & 15) * 256;
  // staging per-lane source (pre-swizzled chunk; low3(row) invariant under
  // +64/+128 row offsets, so one chunk index serves all halves/calls)
  const int row0 = tid >> 3;  // 0..63 within a stage call
  const int c0 = (tid & 7) ^ (row0 & 7);
  const unsigned short* aSrc = A + (size_t)(m0 + row0) * K1_LDA + c0 * 8;
  const unsigned short* bSrc = B + (size_t)(n0 + row0) * K1_LDA + c0 * 8;
  // fragment coords
  const int q = l >> 4, mr = l & 15;
  const int wm = w >> 2, wn = w & 3;

  // prologue: tile0 (4 halves) then tile1 {B.h0,B.h1,A.h0}; wait so tile0's
  // 8 loads (the oldest) are landed, 3 half-tiles outstanding.
  K1_STG(aSrc, As, 0, 0);
  K1_STG(aSrc, As, 0, 1);
  K1_STG(bSrc, Bs, 0, 0);
  K1_STG(bSrc, Bs, 0, 1);
  K1_STG(bSrc, Bs, 1, 0);
  K1_STG(bSrc, Bs, 1, 1);
  K1_STG(aSrc, As, 1, 0);
  asm volatile("s_waitcnt vmcnt(6)" ::: "memory");
  asm volatile("s_barrier" ::: "memory");

  f32x4 acc[8][4] = {};
  for (int t = 0; t < K1_NT; ++t) {
    const int tb = (t & 1) * 2;
    // ---- P1 ds_reads: all B frags (8) + A frags mi{0,1} (4) = 12 reads
    short8 bfr[4][2];
#pragma unroll
    for (int ni = 0; ni < 4; ++ni)
#pragma unroll
      for (int kk = 0; kk < 2; ++kk) {
        const int r = (wn & 1) * 64 + ni * 16 + mr;
        const int c = kk * 4 + q;
        bfr[ni][kk] = *(const short8*)&Bs[(tb + (wn >> 1)) * 8192 + r * 64 +
                                          ((c ^ (r & 7)) * 8)];
      }
#pragma unroll
    for (int p = 0; p < 4; ++p) {
      short8 af[2][2];
#pragma unroll
      for (int i = 0; i < 2; ++i)
#pragma unroll
        for (int kk = 0; kk < 2; ++kk) {
          const int r = (2 * p + i) * 16 + mr;
          const int c = kk * 4 + q;
          af[i][kk] = *(const short8*)&As[(tb + wm) * 8192 + r * 64 +
                                          ((c ^ (r & 7)) * 8)];
        }
      // stage one half-tile (issued after this phase's ds_reads)
      if (p == 0) {
        if (t + 1 < K1_NT) K1_STG(aSrc, As, t + 1, 1);
      } else if (p == 1) {
        if (t + 2 < K1_NT) K1_STG(bSrc, Bs, t + 2, 0);
      } else if (p == 2) {
        if (t + 2 < K1_NT) K1_STG(bSrc, Bs, t + 2, 1);
      } else {
        if (t + 2 < K1_NT) K1_STG(aSrc, As, t + 2, 0);
      }
      asm volatile("s_barrier" ::: "memory");
      __builtin_amdgcn_s_setprio(1);
#pragma unroll
      for (int i = 0; i < 2; ++i)
#pragma unroll
        for (int ni = 0; ni < 4; ++ni)
#pragma unroll
          for (int kk = 0; kk < 2; ++kk)
            acc[2 * p + i][ni] = __builtin_amdgcn_mfma_f32_16x16x32_bf16(
                af[i][kk], bfr[ni][kk], acc[2 * p + i][ni], 0, 0, 0);
      __builtin_amdgcn_s_setprio(0);
      if (p == 3) {
        if (t + 2 < K1_NT) {
          asm volatile("s_waitcnt vmcnt(6)" ::: "memory");
        } else {
          asm volatile("s_waitcnt vmcnt(0)" ::: "memory");
        }
      }
      asm volatile("s_barrier" ::: "memory");
    }
  }
  // epilogue: C/D layout col=lane&15, row=(lane>>4)*4+reg  [m89/m91]
#pragma unroll
  for (int mi = 0; mi < 8; ++mi) {
#pragma unroll
    for (int ni = 0; ni < 4; ++ni) {
      const int row = m0 + wm * 128 + mi * 16 + q * 4;
      const int col = n0 + wn * 64 + ni * 16 + mr;
      const size_t off0 = (size_t)row * 4096 + col;
      const unsigned int p01 = f2bf_pk(acc[mi][ni][0], acc[mi][ni][1]);
      const unsigned int p23 = f2bf_pk(acc[mi][ni][2], acc[mi][ni][3]);
      C[off0] = (unsigned short)p01;
      C[off0 + 4096] = (unsigned short)(p01 >> 16);
      C[off0 + 2 * 4096] = (unsigned short)p23;
      C[off0 + 3 * 4096] = (unsigned short)(p23 >> 16);
    }
  }
}

// ---------------------------------------------------------------------------
// K6: out = y @ out_proj_w^T (M=8192, N=1024, K=2048), K1's schedule at
// BM=256 BN=128 BK=64. R4: verified. Untouched.
// ---------------------------------------------------------------------------
#define K6_LDA 2048
#define K6_NT 32  // K/64

#define K6_STGA(t_, h_)                                                 \
  {                                                                     \
    const unsigned short* s_ =                                          \
        aSrc + (size_t)(h_) * (128 * K6_LDA) + (size_t)(t_) * 64;       \
    unsigned short* d_ = As + (((t_) & 1) * 2 + (h_)) * 8192 + w * 512; \
    gl_lds16(s_, d_);                                                   \
    gl_lds16(s_ + 64 * K6_LDA, d_ + 4096);                              \
  }
#define K6_STGB(t_)                                            \
  {                                                            \
    const unsigned short* s_ = bSrc + (size_t)(t_) * 64;       \
    unsigned short* d_ = Bs6 + ((t_) & 1) * 8192 + w * 512;    \
    gl_lds16(s_, d_);                                          \
    gl_lds16(s_ + 64 * K6_LDA, d_ + 4096);                     \
  }

__global__ __launch_bounds__(512, 2) void gemm256x128_k6(
    const unsigned short* __restrict__ A,  // ybf 8192 x 2048 bf16
    const unsigned short* __restrict__ B,  // opw 1024 x 2048 bf16 (row = n)
    void* __restrict__ C,                  // out 8192 x 1024 (f32 or bf16)
    const int* __restrict__ flag) {
  __shared__ unsigned short As[32768];   // [buf][half][128][64]
  __shared__ unsigned short Bs6[16384];  // [buf][128][64]
  const int tid = threadIdx.x;
  const int l = tid & 63, w = tid >> 6;
  // XCD-bijective swizzle: 256 wgs, 8 XCDs, 32 contiguous per XCD.
  const int bid = blockIdx.x;
  const int swz = (bid & 7) * 32 + (bid >> 3);
  const int n0 = (swz & 7) * 128, m0 = (swz >> 3) * 256;
  const int row0 = tid >> 3;  // 0..63 within a stage call
  const int c0 = (tid & 7) ^ (row0 & 7);
  const unsigned short* aSrc = A + (size_t)(m0 + row0) * K6_LDA + c0 * 8;
  const unsigned short* bSrc = B + (size_t)(n0 + row0) * K6_LDA + c0 * 8;
  // fragment coords
  const int q = l >> 4, mr = l & 15;
  const int wm = w >> 2, wn = w & 3;

  // prologue: tile0 {A.h0,A.h1,B}, tile1 {B, A.h0}; vmcnt(4) -> tile0 landed,
  // {B(1), A.h0(1)} (4 loads) in flight.
  K6_STGA(0, 0);
  K6_STGA(0, 1);
  K6_STGB(0);
  K6_STGB(1);
  K6_STGA(1, 0);
  asm volatile("s_waitcnt vmcnt(4)" ::: "memory");
  asm volatile("s_barrier" ::: "memory");

  f32x4 acc[8][2] = {};
  for (int t = 0; t < K6_NT; ++t) {
    const int tb = (t & 1) * 2;
    // B frags for this tile (4 reads)
    short8 bfr[2][2];
#pragma unroll
    for (int ni = 0; ni < 2; ++ni)
#pragma unroll
      for (int kk = 0; kk < 2; ++kk) {
        const int r = wn * 32 + ni * 16 + mr;
        const int c = kk * 4 + q;
        bfr[ni][kk] = *(const short8*)&Bs6[(t & 1) * 8192 + r * 64 +
                                           ((c ^ (r & 7)) * 8)];
      }
#pragma unroll
    for (int p = 0; p < 4; ++p) {
      short8 af[2][2];
#pragma unroll
      for (int i = 0; i < 2; ++i)
#pragma unroll
        for (int kk = 0; kk < 2; ++kk) {
          const int r = (2 * p + i) * 16 + mr;
          const int c = kk * 4 + q;
          af[i][kk] = *(const short8*)&As[(tb + wm) * 8192 + r * 64 +
                                          ((c ^ (r & 7)) * 8)];
        }
      // stage schedule
      if (p == 0) {
        if (t + 1 < K6_NT) K6_STGA(t + 1, 1);
      } else if (p == 1) {
        if (t + 2 < K6_NT) K6_STGB(t + 2);
      } else if (p == 3) {
        if (t + 2 < K6_NT) K6_STGA(t + 2, 0);
      }
      asm volatile("s_barrier" ::: "memory");
      __builtin_amdgcn_s_setprio(1);
#pragma unroll
      for (int i = 0; i < 2; ++i)
#pragma unroll
        for (int ni = 0; ni < 2; ++ni)
#pragma unroll
          for (int kk = 0; kk < 2; ++kk)
            acc[2 * p + i][ni] = __builtin_amdgcn_mfma_f32_16x16x32_bf16(
                af[i][kk], bfr[ni][kk], acc[2 * p + i][ni], 0, 0, 0);
      __builtin_amdgcn_s_setprio(0);
      if (p == 3) {
        if (t + 2 < K6_NT) {
          asm volatile("s_waitcnt vmcnt(4)" ::: "memory");
        } else {
          asm volatile("s_waitcnt vmcnt(0)" ::: "memory");
        }
      }
      asm volatile("s_barrier" ::: "memory");
    }
  }
  // epilogue: C/D layout col=lane&15, row=(lane>>4)*4+reg  [m89/m91]
  const int bf = *flag;
#pragma unroll
  for (int mi = 0; mi < 8; ++mi) {
#pragma unroll
    for (int ni = 0; ni < 2; ++ni) {
      const int row = m0 + wm * 128 + mi * 16 + q * 4;
      const int col = n0 + wn * 32 + ni * 16 + mr;
      const size_t off0 = (size_t)row * 1024 + col;
      if (bf) {
        const unsigned int p01 = f2bf_pk(acc[mi][ni][0], acc[mi][ni][1]);
        const unsigned int p23 = f2bf_pk(acc[mi][ni][2], acc[mi][ni][3]);
        unsigned short* C16 = (unsigned short*)C;
        C16[off0] = (unsigned short)p01;
        C16[off0 + 1024] = (unsigned short)(p01 >> 16);
        C16[off0 + 2 * 1024] = (unsigned short)p23;
        C16[off0 + 3 * 1024] = (unsigned short)(p23 >> 16);
      } else {
        float* Cf = (float*)C;
#pragma unroll
        for (int j = 0; j < 4; ++j)
          Cf[off0 + (size_t)j * 1024] = acc[mi][ni][j];
      }
    }
  }
}

// ---------------------------------------------------------------------------
// K3: split-K x4 + reduce. 128x128 tile, BK=32, 4 waves, EPI3 split-K
// partials. Untouched.
// ---------------------------------------------------------------------------
template <int EPI, int TAG>
__global__ __launch_bounds__(256) void gemm_mfma(
    const unsigned short* __restrict__ Ain, int lda,
    const unsigned short* __restrict__ Bin, int ldb, void* __restrict__ C,
    int ldc, int K, const void* __restrict__ bias,
    const int* __restrict__ flag) {
  __shared__ unsigned short As[128 * 32];
  __shared__ unsigned short Bs[128 * 32];
  const unsigned short* A = Ain;
  const unsigned short* B = Bin;
  if (EPI == 3) {  // split-K slice
    A += (size_t)blockIdx.z * 512;
    B += (size_t)blockIdx.z * 512;
  }
  const int tid = threadIdx.x;
  const int l = tid & 63, w = tid >> 6;
  const int bm = blockIdx.y * 128;
  const int bn = blockIdx.x * 128;
  // staging: lane l of wave w covers row (w*16 + l/4); swizzled k-chunk.
  const int r0 = w * 16 + (l >> 2);
  const int cc = (((l & 3) ^ ((l >> 2) & 3) ^ ((l >> 4) & 3))) * 8;
  const unsigned short* Ap0 = A + (size_t)(bm + r0) * lda + cc;
  const unsigned short* Ap1 = A + (size_t)(bm + r0 + 64) * lda + cc;
  const unsigned short* Bp0 = B + (size_t)(bn + r0) * ldb + cc;
  const unsigned short* Bp1 = B + (size_t)(bn + r0 + 64) * ldb + cc;
  // fragment coords
  const int q = l >> 4, mr = l & 15;
  const int wm = w >> 1, wn = w & 1;
  const int slot = (q ^ (mr & 3) ^ (mr >> 2)) * 8;  // swizzled k-slot
  f32x4 acc[4][4] = {};
  for (int k0 = 0; k0 < K; k0 += 32) {
    gl_lds16(Ap0 + k0, As + w * 512);
    gl_lds16(Ap1 + k0, As + 2048 + w * 512);
    gl_lds16(Bp0 + k0, Bs + w * 512);
    gl_lds16(Bp1 + k0, Bs + 2048 + w * 512);
    __syncthreads();  // drains vmcnt (global_load_lds)
    short8 af[4], bfr[4];
#pragma unroll
    for (int mi = 0; mi < 4; ++mi)
      af[mi] = *(const short8*)&As[(wm * 64 + mi * 16 + mr) * 32 + slot];
#pragma unroll
    for (int ni = 0; ni < 4; ++ni)
      bfr[ni] = *(const short8*)&Bs[(wn * 64 + ni * 16 + mr) * 32 + slot];
#pragma unroll
    for (int mi = 0; mi < 4; ++mi)
#pragma unroll
      for (int ni = 0; ni < 4; ++ni)
        acc[mi][ni] = __builtin_amdgcn_mfma_f32_16x16x32_bf16(
            af[mi], bfr[ni], acc[mi][ni], 0, 0, 0);
    __syncthreads();
  }
  // epilogue: C/D layout col=lane&15, row=(lane>>4)*4+reg  [m89/m91]
  float* Cp3 = (EPI == 3)
                   ? ((float*)C + (size_t)blockIdx.z * ML * 128)
                   : (float*)C;
#pragma unroll
  for (int mi = 0; mi < 4; ++mi) {
#pragma unroll
    for (int ni = 0; ni < 4; ++ni) {
      const int row = bm + wm * 64 + mi * 16 + q * 4;
      const int col = bn + wn * 64 + ni * 16 + mr;
      const size_t off0 = (size_t)row * ldc + col;
      if (EPI == 3) {
#pragma unroll
        for (int j = 0; j < 4; ++j)
          Cp3[off0 + (size_t)j * ldc] = acc[mi][ni][j];
      } else {
        const unsigned int p01 = f2bf_pk(acc[mi][ni][0], acc[mi][ni][1]);
        const unsigned int p23 = f2bf_pk(acc[mi][ni][2], acc[mi][ni][3]);
        unsigned short* C16 = (unsigned short*)C;
        C16[off0] = (unsigned short)p01;
        C16[off0 + ldc] = (unsigned short)(p01 >> 16);
        C16[off0 + 2 * (size_t)ldc] = (unsigned short)p23;
        C16[off0 + 3 * (size_t)ldc] = (unsigned short)(p23 >> 16);
      }
    }
  }
}

// Split-K reduce: dbl = bf16(sum of 4 f32 partials). 1M elems, 4/thread.
__global__ __launch_bounds__(256) void reduceK3_kernel(
    const float* __restrict__ part, unsigned short* __restrict__ dbl) {
  const size_t i = (size_t)(blockIdx.x * 256 + threadIdx.x) * 4;
  const size_t st = (size_t)ML * 128;
  float4 a = *(const float4*)(part + i);
  float4 b = *(const float4*)(part + st + i);
  float4 c = *(const float4*)(part + 2 * st + i);
  float4 d = *(const float4*)(part + 3 * st + i);
  uint2 v;
  v.x = f2bf_pk(a.x + b.x + c.x + d.x, a.y + b.y + c.y + d.y);
  v.y = f2bf_pk(a.z + b.z + c.z + d.z, a.w + b.w + c.w + d.w);
  *(uint2*)(dbl + i) = v;
}

// ---------------------------------------------------------------------------
// K4 (R11): dt = softplus(dbl[:,0:64] @ dtw^T + b) -> xzb x-half (ldc=4096).
// R10 counters exposed the old persistent-B design: Occupancy 10.9% (4
// waves/CU), 405 GB/s, 94 us — store latency uncovered. New: grid
// (16 n x 64 m) = 1024 wgs = 4 blocks/CU = 16 waves/CU; each block stages
// B(128x64)+A(128x64) once (32 KiB LDS), vmcnt(0)+barrier, 32 MFMAs,
// softplus epilogue. Latency hidden by inter-block TLP (m114 overlap).
// Same XOR chunk swizzle both-sides. Numerics identical to R8/R10.
// ---------------------------------------------------------------------------
__global__ __launch_bounds__(256) void dt_gemm_kernel(
    const unsigned short* __restrict__ Adbl,  // (ML,128) bf16, cols 0:64 used
    const unsigned short* __restrict__ Bw,    // (2048,64) bf16
    unsigned short* __restrict__ Cdt,         // xzb base; ldc=4096, x-half
    const void* __restrict__ bias, const int* __restrict__ flag) {
  __shared__ unsigned short Bs[128 * 64];  // 16 KiB
  __shared__ unsigned short As[128 * 64];  // 16 KiB
  const int tid = threadIdx.x;
  const int l = tid & 63, w = tid >> 6;
  const int bn = blockIdx.x * 128;  // n-tile
  const int mg = blockIdx.y * 128;  // m-tile
  // staging: per call, 256 thr cover 32 rows x 64 cols (128B rows);
  // pre-swizzled source chunk (row&7 invariant under +32 row offsets).
  const int srow = tid >> 3;                    // 0..31
  const int sc = ((tid & 7) ^ (srow & 7)) * 8;  // chunk involution
  const unsigned short* aSrc = Adbl + (size_t)(mg + srow) * 128 + sc;
  const unsigned short* bSrc = Bw + (size_t)(bn + srow) * 64 + sc;
#pragma unroll
  for (int i = 0; i < 4; ++i)
    gl_lds16(bSrc + (size_t)i * 32 * 64, Bs + i * 2048 + w * 512);
#pragma unroll
  for (int i = 0; i < 4; ++i)
    gl_lds16(aSrc + (size_t)i * 32 * 128, As + i * 2048 + w * 512);
  asm volatile("s_waitcnt vmcnt(0)" ::: "memory");
  asm volatile("s_barrier" ::: "memory");
  // fragment coords: 4 waves = 2M x 2N, wave tile 64x64
  const int q = l >> 4, mr = l & 15;
  const int wm = w >> 1, wn = w & 1;
  const int bf = *flag;
  short8 af[4][2], bfr[4][2];
#pragma unroll
  for (int ni = 0; ni < 4; ++ni)
#pragma unroll
    for (int kk = 0; kk < 2; ++kk) {
      const int r = wn * 64 + ni * 16 + mr;
      const int c = kk * 4 + q;
      bfr[ni][kk] = *(const short8*)&Bs[r * 64 + ((c ^ (r & 7)) * 8)];
    }
#pragma unroll
  for (int mi = 0; mi < 4; ++mi)
#pragma unroll
    for (int kk = 0; kk < 2; ++kk) {
      const int r = wm * 64 + mi * 16 + mr;
      const int c = kk * 4 + q;
      af[mi][kk] = *(const short8*)&As[r * 64 + ((c ^ (r & 7)) * 8)];
    }
  f32x4 acc[4][4] = {};
#pragma unroll
  for (int mi = 0; mi < 4; ++mi)
#pragma unroll
    for (int ni = 0; ni < 4; ++ni)
#pragma unroll
      for (int kk = 0; kk < 2; ++kk)
        acc[mi][ni] = __builtin_amdgcn_mfma_f32_16x16x32_bf16(
            af[mi][kk], bfr[ni][kk], acc[mi][ni], 0, 0, 0);
  // epilogue: softplus + bf16 store (C/D layout m89/m91)
#pragma unroll
  for (int mi = 0; mi < 4; ++mi) {
#pragma unroll
    for (int ni = 0; ni < 4; ++ni) {
      const int row = mg + wm * 64 + mi * 16 + q * 4;
      const int col = bn + wn * 64 + ni * 16 + mr;
      const size_t off0 = (size_t)row * 4096 + col;
      const float bv = bf ? ld1<true>(bias, col) : ld1<false>(bias, col);
      float v[4];
#pragma unroll
      for (int j = 0; j < 4; ++j) {
        const float t = acc[mi][ni][j] + bv;
        v[j] = fmaxf(t, 0.f) + __logf(1.f + __expf(-fabsf(t)));
      }
      const unsigned int p01 = f2bf_pk(v[0], v[1]);
      const unsigned int p23 = f2bf_pk(v[2], v[3]);
      Cdt[off0] = (unsigned short)p01;
      Cdt[off0 + 4096] = (unsigned short)(p01 >> 16);
      Cdt[off0 + 2 * 4096] = (unsigned short)p23;
      Cdt[off0 + 3 * 4096] = (unsigned short)(p23 >> 16);
    }
  }
}

// ---------------------------------------------------------------------------
// Depthwise causal conv (width 4) + bias + SiLU, 4 channels per thread.
// xzb: (ML,4096) bf16; x part = cols [0,2048). Output xcb (ML,2048) bf16.
// ---------------------------------------------------------------------------
__global__ __launch_bounds__(256) void conv_silu_kernel(
    const unsigned short* __restrict__ xzb, const void* __restrict__ cw,
    const void* __restrict__ cb, unsigned short* __restrict__ xcb,
    const int* __restrict__ flag) {
  const int bf = *flag;
  const int e = (blockIdx.x * 256 + threadIdx.x) * 4;  // over ML*D_INNER
  const int d = e & (D_INNER - 1);
  const int bl = e >> 11;
  const int l = bl & (SEQ - 1);
  const size_t base = (size_t)bl * 4096 + d;
  float x0[4], x1[4] = {}, x2[4] = {}, x3[4] = {};
  ld4<true>(xzb, base, x0);
  if (l >= 1) ld4<true>(xzb, base - 4096, x1);
  if (l >= 2) ld4<true>(xzb, base - 2 * 4096, x2);
  if (l >= 3) ld4<true>(xzb, base - 3 * 4096, x3);
  float r[4];
#pragma unroll
  for (int i = 0; i < 4; ++i) {
    float w[4];
    if (bf) ld4<true>(cw, (size_t)(d + i) * 4, w);
    else ld4<false>(cw, (size_t)(d + i) * 4, w);
    const float bias = bf ? ld1<true>(cb, d + i) : ld1<false>(cb, d + i);
    float acc = bias + w[3] * x0[i] + w[2] * x1[i] + w[1] * x2[i] + w[0] * x3[i];
    r[i] = acc / (1.f + __expf(-acc));  // silu
  }
  uint2 o;
  o.x = f2bf_pk(r[0], r[1]);
  o.y = f2bf_pk(r[2], r[3]);
  *(uint2*)(xcb + e) = o;
}

// ---------------------------------------------------------------------------
// Chunked selective scan, thread-per-channel, h[16] in VGPRs (R8 version,
// restored: the R9 2-way split turned passC VALU-bound (80% busy, 94 us) —
// duplicated loads/exp/addressing + shfl outweighed the occupancy gain).
// NCH=64 (CL=32). S layout [b][c][n][d]; P recomputed in passB from sdt.
// ---------------------------------------------------------------------------
__device__ __forceinline__ void load_a(const void* A_log, int bf, int d,
                                       float a[16], float& dev) {
  float t[4];
#pragma unroll
  for (int k = 0; k < 4; ++k) {
    if (bf) ld4<true>(A_log, (size_t)d * 16 + k * 4, t);
    else ld4<false>(A_log, (size_t)d * 16 + k * 4, t);
#pragma unroll
    for (int j = 0; j < 4; ++j) a[k * 4 + j] = -expf(t[j]);
  }
  dev = 0.f;
#pragma unroll
  for (int n = 0; n < 16; ++n) dev = fmaxf(dev, fabsf(a[n] + (float)(n + 1)));
}

// powers pw[n] = e1^(n+1), log-depth tree (max dep ~5)
__device__ __forceinline__ void pow_tree(float e1, float pw[16]) {
  const float e2 = e1 * e1;
  const float e3 = e2 * e1;
  const float e4 = e2 * e2;
  pw[0] = e1; pw[1] = e2; pw[2] = e3; pw[3] = e4;
  pw[4] = e4 * e1; pw[5] = e4 * e2; pw[6] = e4 * e3; pw[7] = e4 * e4;
  const float e8 = pw[7];
  pw[8] = e8 * e1; pw[9] = e8 * e2; pw[10] = e8 * e3; pw[11] = e8 * e4;
  pw[12] = e8 * pw[4]; pw[13] = e8 * pw[5]; pw[14] = e8 * pw[6];
  pw[15] = e8 * e8;
}

// Pass A: from h=0, chunk-final state S[b][c][n][d]; sdt per (b,c,d).
__global__ __launch_bounds__(256) void scan_passA(
    const unsigned short* __restrict__ xzb,
    const unsigned short* __restrict__ xcb,
    const unsigned short* __restrict__ dbl, const void* __restrict__ A_log,
    const int* __restrict__ flag, float* __restrict__ S,
    float* __restrict__ Sdt) {
  const int bf = *flag;
  const int gid = blockIdx.x * 256 + threadIdx.x;
  const int d = gid & (D_INNER - 1);
  const int c = (gid >> 11) & (NCH - 1);
  const int b = gid >> (11 + LOG_NCH);
  float a[16], dev;
  load_a(A_log, bf, d, a, dev);
  float h[16] = {};
  float sdt = 0.f;
  const size_t m0 = (size_t)b * SEQ + c * CL;
  if (dev < 1e-3f) {  // integer-decay fast path
    for (int t = 0; t < CL; ++t) {
      const size_t m = m0 + t;
      const float dtv = bf2f(xzb[m * 4096 + d]);
      const float xv = bf2f(xcb[m * 2048 + d]);
      const u16x8 B0 = *(const u16x8*)&dbl[m * 128 + 64];
      const u16x8 B1 = *(const u16x8*)&dbl[m * 128 + 72];
      const float dtx = dtv * xv;
      sdt += dtv;
      float pw[16];
      pow_tree(__expf(-dtv), pw);
#pragma unroll
      for (int n = 0; n < 16; ++n) {
        const float Bv = bf2f(n < 8 ? B0[n] : B1[n - 8]);
        h[n] = fmaf(pw[n], h[n], Bv * dtx);
      }
    }
  } else {
    for (int t = 0; t < CL; ++t) {
      const size_t m = m0 + t;
      const float dtv = bf2f(xzb[m * 4096 + d]);
      const float xv = bf2f(xcb[m * 2048 + d]);
      const u16x8 B0 = *(const u16x8*)&dbl[m * 128 + 64];
      const u16x8 B1 = *(const u16x8*)&dbl[m * 128 + 72];
      const float dtx = dtv * xv;
      sdt += dtv;
#pragma unroll
      for (int n = 0; n < 16; ++n) {
        const float Bv = bf2f(n < 8 ? B0[n] : B1[n - 8]);
        h[n] = fmaf(__expf(dtv * a[n]), h[n], Bv * dtx);
      }
    }
  }
  // coalesced: consecutive threads = consecutive d -> 256B/inst per wave
  const size_t sbase = (((size_t)b * NCH + c) * 16) * D_INNER + d;
#pragma unroll
  for (int n = 0; n < 16; ++n) S[sbase + (size_t)n * D_INNER] = h[n];
  Sdt[((size_t)b * NCH + c) * D_INNER + d] = sdt;
}

// Pass B: serial prefix over NCH chunks; S[c] becomes the INITIAL state of
// chunk c. One thread per (b,n,d) = 131072, d-fast for coalescing.
__global__ __launch_bounds__(256) void scan_passB(
    float* __restrict__ S, const float* __restrict__ Sdt,
    const void* __restrict__ A_log, const int* __restrict__ flag) {
  const int bf = *flag;
  const int idx = blockIdx.x * 256 + threadIdx.x;
  const int d = idx & (D_INNER - 1);
  const int n = (idx >> 11) & 15;
  const int b = idx >> 15;
  const float al = bf ? ld1<true>(A_log, (size_t)d * 16 + n)
                      : ld1<false>(A_log, (size_t)d * 16 + n);
  const float a = -expf(al);
  float h = 0.f;
  for (int c = 0; c < NCH; ++c) {
    const size_t base = ((size_t)b * NCH + c);
    const size_t sidx = (base * 16 + n) * D_INNER + d;
    const float s = S[sidx];
    const float sdt = Sdt[base * D_INNER + d];
    const float p = __expf(a * sdt);
    S[sidx] = h;  // init for chunk c
    h = p * h + s;
  }
}

// Pass C: replay chunk from true init state; y = (sum_n h*C + D*x)*silu(z).
__global__ __launch_bounds__(256) void scan_passC(
    const unsigned short* __restrict__ xzb,
    const unsigned short* __restrict__ xcb,
    const unsigned short* __restrict__ dbl, const void* __restrict__ A_log,
    const void* __restrict__ Dp, const float* __restrict__ S,
    const int* __restrict__ flag, unsigned short* __restrict__ ybf) {
  const int bf = *flag;
  const int gid = blockIdx.x * 256 + threadIdx.x;
  const int d = gid & (D_INNER - 1);
  const int c = (gid >> 11) & (NCH - 1);
  const int b = gid >> (11 + LOG_NCH);
  float a[16], dev;
  load_a(A_log, bf, d, a, dev);
  const float Dv = bf ? ld1<true>(Dp, d) : ld1<false>(Dp, d);
  float h[16];
  const size_t sbase = (((size_t)b * NCH + c) * 16) * D_INNER + d;
#pragma unroll
  for (int n = 0; n < 16; ++n) h[n] = S[sbase + (size_t)n * D_INNER];
  const size_t m0 = (size_t)b * SEQ + c * CL;
  const bool trick = dev < 1e-3f;
  for (int t = 0; t < CL; ++t) {
    const size_t m = m0 + t;
    const float dtv = bf2f(xzb[m * 4096 + d]);
    const float xv = bf2f(xcb[m * 2048 + d]);
    const u16x8 B0 = *(const u16x8*)&dbl[m * 128 + 64];
    const u16x8 B1 = *(const u16x8*)&dbl[m * 128 + 72];
    const u16x8 C0 = *(const u16x8*)&dbl[m * 128 + 80];
    const u16x8 C1 = *(const u16x8*)&dbl[m * 128 + 88];
    const float dtx = dtv * xv;
    float y = 0.f;
    if (trick) {
      float pw[16];
      pow_tree(__expf(-dtv), pw);
#pragma unroll
      for (int n = 0; n < 16; ++n) {
        const float Bv = bf2f(n < 8 ? B0[n] : B1[n - 8]);
        const float Cv = bf2f(n < 8 ? C0[n] : C1[n - 8]);
        h[n] = fmaf(pw[n], h[n], Bv * dtx);
        y = fmaf(h[n], Cv, y);
      }
    } else {
#pragma unroll
      for (int n = 0; n < 16; ++n) {
        const float Bv = bf2f(n < 8 ? B0[n] : B1[n - 8]);
        const float Cv = bf2f(n < 8 ? C0[n] : C1[n - 8]);
        h[n] = fmaf(__expf(dtv * a[n]), h[n], Bv * dtx);
        y = fmaf(h[n], Cv, y);
      }
    }
    const float zv = bf2f(xzb[m * 4096 + 2048 + d]);
    const float yv = y + Dv * xv;
    ybf[m * 2048 + d] = f2bf(yv * (zv / (1.f + __expf(-zv))));
  }
}

// ---------------------------------------------------------------------------
extern "C" void kernel_launch(void* const* d_in, const int* in_sizes, int n_in,
                              void* d_out, int out_size, void* d_ws,
                              size_t ws_size, hipStream_t stream) {
  const void* x = d_in[0];
  const void* in_proj_w = d_in[1];
  const void* conv_w = d_in[2];
  const void* conv_b = d_in[3];
  const void* x_proj_w = d_in[4];
  const void* dt_proj_w = d_in[5];
  const void* dt_proj_b = d_in[6];
  const void* A_log = d_in[7];
  const void* D_param = d_in[8];
  const void* out_proj_w = d_in[9];

  // ws layout:
  // flag 256B | xzb 64MB | xcb 32MB (pre-conv hosts x_bf+ipw_bf) | dbl 2MB |
  // ybf 32MB | S 33.5MB (NCH=64; aliases k3part 16.8MB pre-scan) | Sdt 2MB |
  // opw 4MB | xpw_pad 512KB | dtw 256KB
  char* wsb = (char*)d_ws;
  int* flag = (int*)wsb;
  unsigned short* xzb = (unsigned short*)(wsb + 256);
  unsigned short* xcb = xzb + (size_t)ML * 4096;
  unsigned short* dbl = xcb + (size_t)ML * 2048;
  unsigned short* ybf = dbl + (size_t)ML * 128;
  float* S = (float*)(ybf + (size_t)ML * 2048);
  float* Sdt = S + (size_t)BATCH * NCH * D_INNER * 16;
  unsigned short* opw_bf =
      (unsigned short*)(Sdt + (size_t)BATCH * NCH * D_INNER);
  unsigned short* xpw_pad = opw_bf + (size_t)1024 * 2048;
  unsigned short* dtw_bf = xpw_pad + (size_t)128 * 2048;
  unsigned short* x_bf = xcb;                        // dead after K1
  unsigned short* ipw_bf = xcb + (size_t)ML * 1024;  // dead after K1
  float* k3part = S;  // 4 x (ML x 128) f32 = 16.78 MB; dead before scans

  // fused conversions + inline dtype detection (one dispatch)
  cvt_all_kernel<<<CVT_E4 / 1024, 256, 0, stream>>>(
      x, in_proj_w, out_proj_w, dt_proj_w, x_proj_w, x_bf, ipw_bf, opw_bf,
      dtw_bf, xpw_pad, flag);
  // K1: xz = x @ in_proj_w^T (M=8192,N=4096,K=1024) -> xzb bf16
  gemm256_k1<<<dim3(512), 512, 0, stream>>>(x_bf, ipw_bf, xzb);
  // K2: causal depthwise conv + SiLU -> xcb bf16 (x_bf/ipw_bf now dead)
  conv_silu_kernel<<<(ML * D_INNER) / 1024, 256, 0, stream>>>(
      xzb, conv_w, conv_b, xcb, flag);
  // K3: dbl = xc @ x_proj_w^T (M=8192, N=128(pad), K=2048), split-K x4 ->
  // f32 partials in S region, then reduce+bf16.
  {
    dim3 g(1, ML / 128, 4);
    gemm_mfma<3, 3><<<g, 256, 0, stream>>>(xcb, 2048, xpw_pad, 2048, k3part,
                                           128, 512, nullptr, flag);
  }
  reduceK3_kernel<<<(ML * 128) / 1024, 256, 0, stream>>>(k3part, dbl);
  // K4: dt = softplus(dbl[:,:64] @ dt_proj_w^T + b) -> xzb x-half (ldc=4096)
  // R11: 1024 wgs = 4 blocks/CU (16 waves/CU) single-shot tiles.
  dt_gemm_kernel<<<dim3(16, 64), 256, 0, stream>>>(dbl, dtw_bf, xzb,
                                                   dt_proj_b, flag);
  // K5: chunked scan, NCH=64 (R8 single-thread-per-channel versions)
  scan_passA<<<(BATCH * NCH * D_INNER) / 256, 256, 0, stream>>>(
      xzb, xcb, dbl, A_log, flag, S, Sdt);
  scan_passB<<<(BATCH * D_INNER * 16) / 256, 256, 0, stream>>>(S, Sdt, A_log,
                                                               flag);
  scan_passC<<<(BATCH * NCH * D_INNER) / 256, 256, 0, stream>>>(
      xzb, xcb, dbl, A_log, D_param, S, flag, ybf);
  // K6: out = y @ out_proj_w^T (M=8192,N=1024,K=2048), out dtype per flag
  gemm256x128_k6<<<dim3(256), 512, 0, stream>>>(ybf, opw_bf, d_out, flag);
}

// Round 12
// 421.346 us; speedup vs baseline: 1.1070x; 1.0217x over previous
//
#include <hip/hip_runtime.h>
#include <hip/hip_bf16.h>
#include <math.h>

#define D_MODEL 1024
#define D_STATE 16
#define D_CONV 4
#define D_INNER 2048
#define DT_RANK 64
#define BATCH 4
#define SEQ 2048
#define ML (BATCH * SEQ)  // 8192 rows
#define NCH 64            // scan chunks per sequence
#define LOG_NCH 6
#define CL (SEQ / NCH)    // 32 steps per chunk

typedef __attribute__((ext_vector_type(8))) short short8;
typedef __attribute__((ext_vector_type(8))) unsigned short u16x8;
typedef __attribute__((ext_vector_type(4))) float f32x4;

// ---------------------------------------------------------------------------
// dtype helpers: inputs may be fp32 (expected) or bf16 (runtime-detected).
// ---------------------------------------------------------------------------
__device__ __forceinline__ float bf2f(unsigned short u) {
  union { unsigned int i; float f; } v;
  v.i = ((unsigned int)u) << 16;
  return v.f;
}
__device__ __forceinline__ unsigned short f2bf(float f) {
  union { float f; unsigned int i; } u;
  u.f = f;
  unsigned int r = u.i + 0x7fffu + ((u.i >> 16) & 1u);  // RNE
  return (unsigned short)(r >> 16);
}
// packed f32x2 -> bf16x2 (v_cvt_pk_bf16_f32 on gfx950); low 16 = a, high = b
__device__ __forceinline__ unsigned int f2bf_pk(float a, float b) {
  union { __hip_bfloat162 h; unsigned int u; } cv;
  cv.h = __float22bfloat162_rn(make_float2(a, b));
  return cv.u;
}
template <bool BF>
__device__ __forceinline__ float ld1(const void* p, size_t i) {
  if constexpr (BF) return bf2f(((const unsigned short*)p)[i]);
  else return ((const float*)p)[i];
}
template <bool BF>
__device__ __forceinline__ void ld4(const void* p, size_t i, float o[4]) {
  if constexpr (BF) {
    ushort4 v = *(const ushort4*)((const unsigned short*)p + i);
    o[0] = bf2f(v.x); o[1] = bf2f(v.y); o[2] = bf2f(v.z); o[3] = bf2f(v.w);
  } else {
    float4 v = *(const float4*)((const float*)p + i);
    o[0] = v.x; o[1] = v.y; o[2] = v.z; o[3] = v.w;
  }
}

// async global->LDS, 16 B per lane; lds base must be wave-uniform.
__device__ __forceinline__ void gl_lds16(const unsigned short* g,
                                         unsigned short* l) {
  __builtin_amdgcn_global_load_lds(
      (const __attribute__((address_space(1))) void*)g,
      (__attribute__((address_space(3))) void*)l, 16, 0, 0);
}

// ---------------------------------------------------------------------------
// Fused conversion of all weights/x to bf16 (one dispatch). Dtype detection
// (flag=1 means bf16 inputs) folded in; block 0 publishes flag[0].
// ---------------------------------------------------------------------------
#define CVT_N0 (ML * 1024)
#define CVT_N1 (4096 * 1024)
#define CVT_N2 (1024 * 2048)
#define CVT_N3 (2048 * 64)
#define CVT_N4 (128 * 2048)
#define CVT_E0 CVT_N0
#define CVT_E1 (CVT_E0 + CVT_N1)
#define CVT_E2 (CVT_E1 + CVT_N2)
#define CVT_E3 (CVT_E2 + CVT_N3)
#define CVT_E4 (CVT_E3 + CVT_N4)

__device__ __forceinline__ void cvt4(const void* in, size_t i,
                                     unsigned short* out, size_t o, int bf) {
  if (bf) {
    *(ushort4*)(out + o) = *(const ushort4*)((const unsigned short*)in + i);
  } else {
    float4 f = *(const float4*)((const float*)in + i);
    uint2 v;
    v.x = f2bf_pk(f.x, f.y);
    v.y = f2bf_pk(f.z, f.w);
    *(uint2*)(out + o) = v;
  }
}

__global__ __launch_bounds__(256) void cvt_all_kernel(
    const void* __restrict__ x, const void* __restrict__ ipw,
    const void* __restrict__ opw, const void* __restrict__ dtw,
    const void* __restrict__ xpw, unsigned short* __restrict__ x_bf,
    unsigned short* __restrict__ ipw_bf, unsigned short* __restrict__ opw_bf,
    unsigned short* __restrict__ dtw_bf, unsigned short* __restrict__ xpw_pad,
    int* __restrict__ flag) {
  // inline dtype sniff (same logic as the old detect_kernel)
  __shared__ int cnt;
  if (threadIdx.x == 0) cnt = 0;
  __syncthreads();
  {
    const unsigned int wv = ((const unsigned int*)x)[threadIdx.x];
    const unsigned int e = (wv >> 7) & 0xffu;
    if (e < 100u || e > 145u) atomicAdd(&cnt, 1);
  }
  __syncthreads();
  const int bf = (cnt < 32) ? 1 : 0;
  if (blockIdx.x == 0 && threadIdx.x == 0) flag[0] = bf;

  const size_t g = (size_t)(blockIdx.x * 256 + threadIdx.x) * 4;
  if (g < CVT_E0) {
    cvt4(x, g, x_bf, g, bf);
  } else if (g < CVT_E1) {
    const size_t i = g - CVT_E0;
    cvt4(ipw, i, ipw_bf, i, bf);
  } else if (g < CVT_E2) {
    const size_t i = g - CVT_E1;
    cvt4(opw, i, opw_bf, i, bf);
  } else if (g < CVT_E3) {
    const size_t i = g - CVT_E2;
    cvt4(dtw, i, dtw_bf, i, bf);
  } else if (g < CVT_E4) {
    const size_t i = g - CVT_E3;
    const int row = (int)(i >> 11);
    if (row < 96) {
      cvt4(xpw, i, xpw_pad, i, bf);
    } else {
      ushort4 z = {0, 0, 0, 0};
      *(ushort4*)(xpw_pad + i) = z;
    }
  }
}

// ---------------------------------------------------------------------------
// K1 GEMM, 256x256 8-phase schedule (T1+T2+T3+T4+T5, m201 template):
//   C[8192,4096] bf16 = A[8192,1024] * B[4096,1024]^T, all bf16.
// R2 result: 82.6 us, 834 TF, bank-conflict 0. Left untouched.
// ---------------------------------------------------------------------------
#define K1_LDA 1024
#define K1_NT 16  // K/64

#define K1_STG(srcbase, lds, t_, h_)                                       \
  {                                                                        \
    const unsigned short* s_ =                                             \
        (srcbase) + (size_t)(h_) * (128 * K1_LDA) + (size_t)(t_) * 64;     \
    unsigned short* d_ = (lds) + (((t_) & 1) * 2 + (h_)) * 8192 + w * 512; \
    gl_lds16(s_, d_);                                                      \
    gl_lds16(s_ + 64 * K1_LDA, d_ + 4096);                                 \
  }

__global__ __launch_bounds__(512, 2) void gemm256_k1(
    const unsigned short* __restrict__ A,  // 8192 x 1024 bf16
    const unsigned short* __restrict__ B,  // 4096 x 1024 bf16 (row = n)
    unsigned short* __restrict__ C) {      // 8192 x 4096 bf16
  __shared__ unsigned short As[32768];  // [buf][half][128][64]
  __shared__ unsigned short Bs[32768];
  const int tid = threadIdx.x;
  const int l = tid & 63, w = tid >> 6;
  // XCD-bijective swizzle: 512 wgs, 8 XCDs, 64 contiguous per XCD.
  const int bid = blockIdx.x;
  const int swz = (bid & 7) * 64 + (bid >> 3);
  const int m0 = (swz >> 4) * 256, n0 = (swz & 15) * 256;
  // staging per-lane source (pre-swizzled chunk; low3(row) invariant under
  // +64/+128 row offsets, so one chunk index serves all halves/calls)
  const int row0 = tid >> 3;  // 0..63 within a stage call
  const int c0 = (tid & 7) ^ (row0 & 7);
  const unsigned short* aSrc = A + (size_t)(m0 + row0) * K1_LDA + c0 * 8;
  const unsigned short* bSrc = B + (size_t)(n0 + row0) * K1_LDA + c0 * 8;
  // fragment coords
  const int q = l >> 4, mr = l & 15;
  const int wm = w >> 2, wn = w & 3;

  // prologue: tile0 (4 halves) then tile1 {B.h0,B.h1,A.h0}; wait so tile0's
  // 8 loads (the oldest) are landed, 3 half-tiles outstanding.
  K1_STG(aSrc, As, 0, 0);
  K1_STG(aSrc, As, 0, 1);
  K1_STG(bSrc, Bs, 0, 0);
  K1_STG(bSrc, Bs, 0, 1);
  K1_STG(bSrc, Bs, 1, 0);
  K1_STG(bSrc, Bs, 1, 1);
  K1_STG(aSrc, As, 1, 0);
  asm volatile("s_waitcnt vmcnt(6)" ::: "memory");
  asm volatile("s_barrier" ::: "memory");

  f32x4 acc[8][4] = {};
  for (int t = 0; t < K1_NT; ++t) {
    const int tb = (t & 1) * 2;
    // ---- P1 ds_reads: all B frags (8) + A frags mi{0,1} (4) = 12 reads
    short8 bfr[4][2];
#pragma unroll
    for (int ni = 0; ni < 4; ++ni)
#pragma unroll
      for (int kk = 0; kk < 2; ++kk) {
        const int r = (wn & 1) * 64 + ni * 16 + mr;
        const int c = kk * 4 + q;
        bfr[ni][kk] = *(const short8*)&Bs[(tb + (wn >> 1)) * 8192 + r * 64 +
                                          ((c ^ (r & 7)) * 8)];
      }
#pragma unroll
    for (int p = 0; p < 4; ++p) {
      short8 af[2][2];
#pragma unroll
      for (int i = 0; i < 2; ++i)
#pragma unroll
        for (int kk = 0; kk < 2; ++kk) {
          const int r = (2 * p + i) * 16 + mr;
          const int c = kk * 4 + q;
          af[i][kk] = *(const short8*)&As[(tb + wm) * 8192 + r * 64 +
                                          ((c ^ (r & 7)) * 8)];
        }
      // stage one half-tile (issued after this phase's ds_reads)
      if (p == 0) {
        if (t + 1 < K1_NT) K1_STG(aSrc, As, t + 1, 1);
      } else if (p == 1) {
        if (t + 2 < K1_NT) K1_STG(bSrc, Bs, t + 2, 0);
      } else if (p == 2) {
        if (t + 2 < K1_NT) K1_STG(bSrc, Bs, t + 2, 1);
      } else {
        if (t + 2 < K1_NT) K1_STG(aSrc, As, t + 2, 0);
      }
      asm volatile("s_barrier" ::: "memory");
      __builtin_amdgcn_s_setprio(1);
#pragma unroll
      for (int i = 0; i < 2; ++i)
#pragma unroll
        for (int ni = 0; ni < 4; ++ni)
#pragma unroll
          for (int kk = 0; kk < 2; ++kk)
            acc[2 * p + i][ni] = __builtin_amdgcn_mfma_f32_16x16x32_bf16(
                af[i][kk], bfr[ni][kk], acc[2 * p + i][ni], 0, 0, 0);
      __builtin_amdgcn_s_setprio(0);
      if (p == 3) {
        if (t + 2 < K1_NT) {
          asm volatile("s_waitcnt vmcnt(6)" ::: "memory");
        } else {
          asm volatile("s_waitcnt vmcnt(0)" ::: "memory");
        }
      }
      asm volatile("s_barrier" ::: "memory");
    }
  }
  // epilogue: C/D layout col=lane&15, row=(lane>>4)*4+reg  [m89/m91]
#pragma unroll
  for (int mi = 0; mi < 8; ++mi) {
#pragma unroll
    for (int ni = 0; ni < 4; ++ni) {
      const int row = m0 + wm * 128 + mi * 16 + q * 4;
      const int col = n0 + wn * 64 + ni * 16 + mr;
      const size_t off0 = (size_t)row * 4096 + col;
      const unsigned int p01 = f2bf_pk(acc[mi][ni][0], acc[mi][ni][1]);
      const unsigned int p23 = f2bf_pk(acc[mi][ni][2], acc[mi][ni][3]);
      C[off0] = (unsigned short)p01;
      C[off0 + 4096] = (unsigned short)(p01 >> 16);
      C[off0 + 2 * 4096] = (unsigned short)p23;
      C[off0 + 3 * 4096] = (unsigned short)(p23 >> 16);
    }
  }
}

// ---------------------------------------------------------------------------
// K6: out = y @ out_proj_w^T (M=8192, N=1024, K=2048), K1's schedule at
// BM=256 BN=128 BK=64. R4: verified. Untouched.
// ---------------------------------------------------------------------------
#define K6_LDA 2048
#define K6_NT 32  // K/64

#define K6_STGA(t_, h_)                                                 \
  {                                                                     \
    const unsigned short* s_ =                                          \
        aSrc + (size_t)(h_) * (128 * K6_LDA) + (size_t)(t_) * 64;       \
    unsigned short* d_ = As + (((t_) & 1) * 2 + (h_)) * 8192 + w * 512; \
    gl_lds16(s_, d_);                                                   \
    gl_lds16(s_ + 64 * K6_LDA, d_ + 4096);                              \
  }
#define K6_STGB(t_)                                            \
  {                                                            \
    const unsigned short* s_ = bSrc + (size_t)(t_) * 64;       \
    unsigned short* d_ = Bs6 + ((t_) & 1) * 8192 + w * 512;    \
    gl_lds16(s_, d_);                                          \
    gl_lds16(s_ + 64 * K6_LDA, d_ + 4096);                     \
  }

__global__ __launch_bounds__(512, 2) void gemm256x128_k6(
    const unsigned short* __restrict__ A,  // ybf 8192 x 2048 bf16
    const unsigned short* __restrict__ B,  // opw 1024 x 2048 bf16 (row = n)
    void* __restrict__ C,                  // out 8192 x 1024 (f32 or bf16)
    const int* __restrict__ flag) {
  __shared__ unsigned short As[32768];   // [buf][half][128][64]
  __shared__ unsigned short Bs6[16384];  // [buf][128][64]
  const int tid = threadIdx.x;
  const int l = tid & 63, w = tid >> 6;
  // XCD-bijective swizzle: 256 wgs, 8 XCDs, 32 contiguous per XCD.
  const int bid = blockIdx.x;
  const int swz = (bid & 7) * 32 + (bid >> 3);
  const int n0 = (swz & 7) * 128, m0 = (swz >> 3) * 256;
  const int row0 = tid >> 3;  // 0..63 within a stage call
  const int c0 = (tid & 7) ^ (row0 & 7);
  const unsigned short* aSrc = A + (size_t)(m0 + row0) * K6_LDA + c0 * 8;
  const unsigned short* bSrc = B + (size_t)(n0 + row0) * K6_LDA + c0 * 8;
  // fragment coords
  const int q = l >> 4, mr = l & 15;
  const int wm = w >> 2, wn = w & 3;

  // prologue: tile0 {A.h0,A.h1,B}, tile1 {B, A.h0}; vmcnt(4) -> tile0 landed,
  // {B(1), A.h0(1)} (4 loads) in flight.
  K6_STGA(0, 0);
  K6_STGA(0, 1);
  K6_STGB(0);
  K6_STGB(1);
  K6_STGA(1, 0);
  asm volatile("s_waitcnt vmcnt(4)" ::: "memory");
  asm volatile("s_barrier" ::: "memory");

  f32x4 acc[8][2] = {};
  for (int t = 0; t < K6_NT; ++t) {
    const int tb = (t & 1) * 2;
    // B frags for this tile (4 reads)
    short8 bfr[2][2];
#pragma unroll
    for (int ni = 0; ni < 2; ++ni)
#pragma unroll
      for (int kk = 0; kk < 2; ++kk) {
        const int r = wn * 32 + ni * 16 + mr;
        const int c = kk * 4 + q;
        bfr[ni][kk] = *(const short8*)&Bs6[(t & 1) * 8192 + r * 64 +
                                           ((c ^ (r & 7)) * 8)];
      }
#pragma unroll
    for (int p = 0; p < 4; ++p) {
      short8 af[2][2];
#pragma unroll
      for (int i = 0; i < 2; ++i)
#pragma unroll
        for (int kk = 0; kk < 2; ++kk) {
          const int r = (2 * p + i) * 16 + mr;
          const int c = kk * 4 + q;
          af[i][kk] = *(const short8*)&As[(tb + wm) * 8192 + r * 64 +
                                          ((c ^ (r & 7)) * 8)];
        }
      // stage schedule
      if (p == 0) {
        if (t + 1 < K6_NT) K6_STGA(t + 1, 1);
      } else if (p == 1) {
        if (t + 2 < K6_NT) K6_STGB(t + 2);
      } else if (p == 3) {
        if (t + 2 < K6_NT) K6_STGA(t + 2, 0);
      }
      asm volatile("s_barrier" ::: "memory");
      __builtin_amdgcn_s_setprio(1);
#pragma unroll
      for (int i = 0; i < 2; ++i)
#pragma unroll
        for (int ni = 0; ni < 2; ++ni)
#pragma unroll
          for (int kk = 0; kk < 2; ++kk)
            acc[2 * p + i][ni] = __builtin_amdgcn_mfma_f32_16x16x32_bf16(
                af[i][kk], bfr[ni][kk], acc[2 * p + i][ni], 0, 0, 0);
      __builtin_amdgcn_s_setprio(0);
      if (p == 3) {
        if (t + 2 < K6_NT) {
          asm volatile("s_waitcnt vmcnt(4)" ::: "memory");
        } else {
          asm volatile("s_waitcnt vmcnt(0)" ::: "memory");
        }
      }
      asm volatile("s_barrier" ::: "memory");
    }
  }
  // epilogue: C/D layout col=lane&15, row=(lane>>4)*4+reg  [m89/m91]
  const int bf = *flag;
#pragma unroll
  for (int mi = 0; mi < 8; ++mi) {
#pragma unroll
    for (int ni = 0; ni < 2; ++ni) {
      const int row = m0 + wm * 128 + mi * 16 + q * 4;
      const int col = n0 + wn * 32 + ni * 16 + mr;
      const size_t off0 = (size_t)row * 1024 + col;
      if (bf) {
        const unsigned int p01 = f2bf_pk(acc[mi][ni][0], acc[mi][ni][1]);
        const unsigned int p23 = f2bf_pk(acc[mi][ni][2], acc[mi][ni][3]);
        unsigned short* C16 = (unsigned short*)C;
        C16[off0] = (unsigned short)p01;
        C16[off0 + 1024] = (unsigned short)(p01 >> 16);
        C16[off0 + 2 * 1024] = (unsigned short)p23;
        C16[off0 + 3 * 1024] = (unsigned short)(p23 >> 16);
      } else {
        float* Cf = (float*)C;
#pragma unroll
        for (int j = 0; j < 4; ++j)
          Cf[off0 + (size_t)j * 1024] = acc[mi][ni][j];
      }
    }
  }
}

// ---------------------------------------------------------------------------
// K3: split-K x4 + reduce. 128x128 tile, BK=32, 4 waves, EPI3 split-K
// partials. Untouched.
// ---------------------------------------------------------------------------
template <int EPI, int TAG>
__global__ __launch_bounds__(256) void gemm_mfma(
    const unsigned short* __restrict__ Ain, int lda,
    const unsigned short* __restrict__ Bin, int ldb, void* __restrict__ C,
    int ldc, int K, const void* __restrict__ bias,
    const int* __restrict__ flag) {
  __shared__ unsigned short As[128 * 32];
  __shared__ unsigned short Bs[128 * 32];
  const unsigned short* A = Ain;
  const unsigned short* B = Bin;
  if (EPI == 3) {  // split-K slice
    A += (size_t)blockIdx.z * 512;
    B += (size_t)blockIdx.z * 512;
  }
  const int tid = threadIdx.x;
  const int l = tid & 63, w = tid >> 6;
  const int bm = blockIdx.y * 128;
  const int bn = blockIdx.x * 128;
  // staging: lane l of wave w covers row (w*16 + l/4); swizzled k-chunk.
  const int r0 = w * 16 + (l >> 2);
  const int cc = (((l & 3) ^ ((l >> 2) & 3) ^ ((l >> 4) & 3))) * 8;
  const unsigned short* Ap0 = A + (size_t)(bm + r0) * lda + cc;
  const unsigned short* Ap1 = A + (size_t)(bm + r0 + 64) * lda + cc;
  const unsigned short* Bp0 = B + (size_t)(bn + r0) * ldb + cc;
  const unsigned short* Bp1 = B + (size_t)(bn + r0 + 64) * ldb + cc;
  // fragment coords
  const int q = l >> 4, mr = l & 15;
  const int wm = w >> 1, wn = w & 1;
  const int slot = (q ^ (mr & 3) ^ (mr >> 2)) * 8;  // swizzled k-slot
  f32x4 acc[4][4] = {};
  for (int k0 = 0; k0 < K; k0 += 32) {
    gl_lds16(Ap0 + k0, As + w * 512);
    gl_lds16(Ap1 + k0, As + 2048 + w * 512);
    gl_lds16(Bp0 + k0, Bs + w * 512);
    gl_lds16(Bp1 + k0, Bs + 2048 + w * 512);
    __syncthreads();  // drains vmcnt (global_load_lds)
    short8 af[4], bfr[4];
#pragma unroll
    for (int mi = 0; mi < 4; ++mi)
      af[mi] = *(const short8*)&As[(wm * 64 + mi * 16 + mr) * 32 + slot];
#pragma unroll
    for (int ni = 0; ni < 4; ++ni)
      bfr[ni] = *(const short8*)&Bs[(wn * 64 + ni * 16 + mr) * 32 + slot];
#pragma unroll
    for (int mi = 0; mi < 4; ++mi)
#pragma unroll
      for (int ni = 0; ni < 4; ++ni)
        acc[mi][ni] = __builtin_amdgcn_mfma_f32_16x16x32_bf16(
            af[mi], bfr[ni], acc[mi][ni], 0, 0, 0);
    __syncthreads();
  }
  // epilogue: C/D layout col=lane&15, row=(lane>>4)*4+reg  [m89/m91]
  float* Cp3 = (EPI == 3)
                   ? ((float*)C + (size_t)blockIdx.z * ML * 128)
                   : (float*)C;
#pragma unroll
  for (int mi = 0; mi < 4; ++mi) {
#pragma unroll
    for (int ni = 0; ni < 4; ++ni) {
      const int row = bm + wm * 64 + mi * 16 + q * 4;
      const int col = bn + wn * 64 + ni * 16 + mr;
      const size_t off0 = (size_t)row * ldc + col;
      if (EPI == 3) {
#pragma unroll
        for (int j = 0; j < 4; ++j)
          Cp3[off0 + (size_t)j * ldc] = acc[mi][ni][j];
      } else {
        const unsigned int p01 = f2bf_pk(acc[mi][ni][0], acc[mi][ni][1]);
        const unsigned int p23 = f2bf_pk(acc[mi][ni][2], acc[mi][ni][3]);
        unsigned short* C16 = (unsigned short*)C;
        C16[off0] = (unsigned short)p01;
        C16[off0 + ldc] = (unsigned short)(p01 >> 16);
        C16[off0 + 2 * (size_t)ldc] = (unsigned short)p23;
        C16[off0 + 3 * (size_t)ldc] = (unsigned short)(p23 >> 16);
      }
    }
  }
}

// Split-K reduce: dbl = bf16(sum of 4 f32 partials). 1M elems, 4/thread.
__global__ __launch_bounds__(256) void reduceK3_kernel(
    const float* __restrict__ part, unsigned short* __restrict__ dbl) {
  const size_t i = (size_t)(blockIdx.x * 256 + threadIdx.x) * 4;
  const size_t st = (size_t)ML * 128;
  float4 a = *(const float4*)(part + i);
  float4 b = *(const float4*)(part + st + i);
  float4 c = *(const float4*)(part + 2 * st + i);
  float4 d = *(const float4*)(part + 3 * st + i);
  uint2 v;
  v.x = f2bf_pk(a.x + b.x + c.x + d.x, a.y + b.y + c.y + d.y);
  v.y = f2bf_pk(a.z + b.z + c.z + d.z, a.w + b.w + c.w + d.w);
  *(uint2*)(dbl + i) = v;
}

// ---------------------------------------------------------------------------
// K4 (R11): dt = softplus(dbl[:,0:64] @ dtw^T + b) -> xzb x-half (ldc=4096).
// Grid (16 n x 64 m) = 1024 wgs = 4 blocks/CU = 16 waves/CU; single-shot
// tile, latency hidden by inter-block TLP. R11: verified (left top-5).
// ---------------------------------------------------------------------------
__global__ __launch_bounds__(256) void dt_gemm_kernel(
    const unsigned short* __restrict__ Adbl,  // (ML,128) bf16, cols 0:64 used
    const unsigned short* __restrict__ Bw,    // (2048,64) bf16
    unsigned short* __restrict__ Cdt,         // xzb base; ldc=4096, x-half
    const void* __restrict__ bias, const int* __restrict__ flag) {
  __shared__ unsigned short Bs[128 * 64];  // 16 KiB
  __shared__ unsigned short As[128 * 64];  // 16 KiB
  const int tid = threadIdx.x;
  const int l = tid & 63, w = tid >> 6;
  const int bn = blockIdx.x * 128;  // n-tile
  const int mg = blockIdx.y * 128;  // m-tile
  // staging: per call, 256 thr cover 32 rows x 64 cols (128B rows);
  // pre-swizzled source chunk (row&7 invariant under +32 row offsets).
  const int srow = tid >> 3;                    // 0..31
  const int sc = ((tid & 7) ^ (srow & 7)) * 8;  // chunk involution
  const unsigned short* aSrc = Adbl + (size_t)(mg + srow) * 128 + sc;
  const unsigned short* bSrc = Bw + (size_t)(bn + srow) * 64 + sc;
#pragma unroll
  for (int i = 0; i < 4; ++i)
    gl_lds16(bSrc + (size_t)i * 32 * 64, Bs + i * 2048 + w * 512);
#pragma unroll
  for (int i = 0; i < 4; ++i)
    gl_lds16(aSrc + (size_t)i * 32 * 128, As + i * 2048 + w * 512);
  asm volatile("s_waitcnt vmcnt(0)" ::: "memory");
  asm volatile("s_barrier" ::: "memory");
  // fragment coords: 4 waves = 2M x 2N, wave tile 64x64
  const int q = l >> 4, mr = l & 15;
  const int wm = w >> 1, wn = w & 1;
  const int bf = *flag;
  short8 af[4][2], bfr[4][2];
#pragma unroll
  for (int ni = 0; ni < 4; ++ni)
#pragma unroll
    for (int kk = 0; kk < 2; ++kk) {
      const int r = wn * 64 + ni * 16 + mr;
      const int c = kk * 4 + q;
      bfr[ni][kk] = *(const short8*)&Bs[r * 64 + ((c ^ (r & 7)) * 8)];
    }
#pragma unroll
  for (int mi = 0; mi < 4; ++mi)
#pragma unroll
    for (int kk = 0; kk < 2; ++kk) {
      const int r = wm * 64 + mi * 16 + mr;
      const int c = kk * 4 + q;
      af[mi][kk] = *(const short8*)&As[r * 64 + ((c ^ (r & 7)) * 8)];
    }
  f32x4 acc[4][4] = {};
#pragma unroll
  for (int mi = 0; mi < 4; ++mi)
#pragma unroll
    for (int ni = 0; ni < 4; ++ni)
#pragma unroll
      for (int kk = 0; kk < 2; ++kk)
        acc[mi][ni] = __builtin_amdgcn_mfma_f32_16x16x32_bf16(
            af[mi][kk], bfr[ni][kk], acc[mi][ni], 0, 0, 0);
  // epilogue: softplus + bf16 store (C/D layout m89/m91)
#pragma unroll
  for (int mi = 0; mi < 4; ++mi) {
#pragma unroll
    for (int ni = 0; ni < 4; ++ni) {
      const int row = mg + wm * 64 + mi * 16 + q * 4;
      const int col = bn + wn * 64 + ni * 16 + mr;
      const size_t off0 = (size_t)row * 4096 + col;
      const float bv = bf ? ld1<true>(bias, col) : ld1<false>(bias, col);
      float v[4];
#pragma unroll
      for (int j = 0; j < 4; ++j) {
        const float t = acc[mi][ni][j] + bv;
        v[j] = fmaxf(t, 0.f) + __logf(1.f + __expf(-fabsf(t)));
      }
      const unsigned int p01 = f2bf_pk(v[0], v[1]);
      const unsigned int p23 = f2bf_pk(v[2], v[3]);
      Cdt[off0] = (unsigned short)p01;
      Cdt[off0 + 4096] = (unsigned short)(p01 >> 16);
      Cdt[off0 + 2 * 4096] = (unsigned short)p23;
      Cdt[off0 + 3 * 4096] = (unsigned short)(p23 >> 16);
    }
  }
}

// ---------------------------------------------------------------------------
// Depthwise causal conv (width 4) + bias + SiLU, 4 channels per thread.
// xzb: (ML,4096) bf16; x part = cols [0,2048). Output xcb (ML,2048) bf16.
// ---------------------------------------------------------------------------
__global__ __launch_bounds__(256) void conv_silu_kernel(
    const unsigned short* __restrict__ xzb, const void* __restrict__ cw,
    const void* __restrict__ cb, unsigned short* __restrict__ xcb,
    const int* __restrict__ flag) {
  const int bf = *flag;
  const int e = (blockIdx.x * 256 + threadIdx.x) * 4;  // over ML*D_INNER
  const int d = e & (D_INNER - 1);
  const int bl = e >> 11;
  const int l = bl & (SEQ - 1);
  const size_t base = (size_t)bl * 4096 + d;
  float x0[4], x1[4] = {}, x2[4] = {}, x3[4] = {};
  ld4<true>(xzb, base, x0);
  if (l >= 1) ld4<true>(xzb, base - 4096, x1);
  if (l >= 2) ld4<true>(xzb, base - 2 * 4096, x2);
  if (l >= 3) ld4<true>(xzb, base - 3 * 4096, x3);
  float r[4];
#pragma unroll
  for (int i = 0; i < 4; ++i) {
    float w[4];
    if (bf) ld4<true>(cw, (size_t)(d + i) * 4, w);
    else ld4<false>(cw, (size_t)(d + i) * 4, w);
    const float bias = bf ? ld1<true>(cb, d + i) : ld1<false>(cb, d + i);
    float acc = bias + w[3] * x0[i] + w[2] * x1[i] + w[1] * x2[i] + w[0] * x3[i];
    r[i] = acc / (1.f + __expf(-acc));  // silu
  }
  uint2 o;
  o.x = f2bf_pk(r[0], r[1]);
  o.y = f2bf_pk(r[2], r[3]);
  *(uint2*)(xcb + e) = o;
}

// ---------------------------------------------------------------------------
// Chunked selective scan, thread-per-channel, h[16] in VGPRs.
// R12: dbl's B/C rows are block-shared (all 256 threads in a block cover the
// same (b,c) chunk) — cooperatively convert them ONCE to f32 in LDS instead
// of 32 redundant per-thread bf2f VALU shifts per step (~40% of passC VALU).
// Reads in the main loop are same-address broadcasts (conflict-free).
// NCH=64 (CL=32). S layout [b][c][n][d]; P recomputed in passB from sdt.
// ---------------------------------------------------------------------------
__device__ __forceinline__ void load_a(const void* A_log, int bf, int d,
                                       float a[16], float& dev) {
  float t[4];
#pragma unroll
  for (int k = 0; k < 4; ++k) {
    if (bf) ld4<true>(A_log, (size_t)d * 16 + k * 4, t);
    else ld4<false>(A_log, (size_t)d * 16 + k * 4, t);
#pragma unroll
    for (int j = 0; j < 4; ++j) a[k * 4 + j] = -expf(t[j]);
  }
  dev = 0.f;
#pragma unroll
  for (int n = 0; n < 16; ++n) dev = fmaxf(dev, fabsf(a[n] + (float)(n + 1)));
}

// powers pw[n] = e1^(n+1), log-depth tree (max dep ~5)
__device__ __forceinline__ void pow_tree(float e1, float pw[16]) {
  const float e2 = e1 * e1;
  const float e3 = e2 * e1;
  const float e4 = e2 * e2;
  pw[0] = e1; pw[1] = e2; pw[2] = e3; pw[3] = e4;
  pw[4] = e4 * e1; pw[5] = e4 * e2; pw[6] = e4 * e3; pw[7] = e4 * e4;
  const float e8 = pw[7];
  pw[8] = e8 * e1; pw[9] = e8 * e2; pw[10] = e8 * e3; pw[11] = e8 * e4;
  pw[12] = e8 * pw[4]; pw[13] = e8 * pw[5]; pw[14] = e8 * pw[6];
  pw[15] = e8 * e8;
}

// Pass A: from h=0, chunk-final state S[b][c][n][d]; sdt per (b,c,d).
__global__ __launch_bounds__(256) void scan_passA(
    const unsigned short* __restrict__ xzb,
    const unsigned short* __restrict__ xcb,
    const unsigned short* __restrict__ dbl, const void* __restrict__ A_log,
    const int* __restrict__ flag, float* __restrict__ S,
    float* __restrict__ Sdt) {
  __shared__ float Bsh[CL][16];  // 2 KiB, block-shared B rows (f32)
  const int bf = *flag;
  const int gid = blockIdx.x * 256 + threadIdx.x;
  const int d = gid & (D_INNER - 1);
  const int c = (gid >> 11) & (NCH - 1);
  const int b = gid >> (11 + LOG_NCH);
  const size_t m0 = (size_t)b * SEQ + c * CL;
  // cooperative fill: CL*16 = 512 values, 2 per thread
  {
    const int tid = threadIdx.x;
#pragma unroll
    for (int k = 0; k < (CL * 16) / 256; ++k) {
      const int idx = tid + k * 256;
      const int t = idx >> 4, n = idx & 15;
      Bsh[t][n] = bf2f(dbl[(m0 + t) * 128 + 64 + n]);
    }
  }
  float a[16], dev;
  load_a(A_log, bf, d, a, dev);
  __syncthreads();
  float h[16] = {};
  float sdt = 0.f;
  if (dev < 1e-3f) {  // integer-decay fast path
    for (int t = 0; t < CL; ++t) {
      const size_t m = m0 + t;
      const float dtv = bf2f(xzb[m * 4096 + d]);
      const float xv = bf2f(xcb[m * 2048 + d]);
      const float dtx = dtv * xv;
      sdt += dtv;
      float pw[16];
      pow_tree(__expf(-dtv), pw);
      const f32x4 B0 = *(const f32x4*)&Bsh[t][0];
      const f32x4 B1 = *(const f32x4*)&Bsh[t][4];
      const f32x4 B2 = *(const f32x4*)&Bsh[t][8];
      const f32x4 B3 = *(const f32x4*)&Bsh[t][12];
#pragma unroll
      for (int j = 0; j < 4; ++j) {
        h[j] = fmaf(pw[j], h[j], B0[j] * dtx);
        h[4 + j] = fmaf(pw[4 + j], h[4 + j], B1[j] * dtx);
        h[8 + j] = fmaf(pw[8 + j], h[8 + j], B2[j] * dtx);
        h[12 + j] = fmaf(pw[12 + j], h[12 + j], B3[j] * dtx);
      }
    }
  } else {
    for (int t = 0; t < CL; ++t) {
      const size_t m = m0 + t;
      const float dtv = bf2f(xzb[m * 4096 + d]);
      const float xv = bf2f(xcb[m * 2048 + d]);
      const float dtx = dtv * xv;
      sdt += dtv;
#pragma unroll
      for (int n = 0; n < 16; ++n)
        h[n] = fmaf(__expf(dtv * a[n]), h[n], Bsh[t][n] * dtx);
    }
  }
  // coalesced: consecutive threads = consecutive d -> 256B/inst per wave
  const size_t sbase = (((size_t)b * NCH + c) * 16) * D_INNER + d;
#pragma unroll
  for (int n = 0; n < 16; ++n) S[sbase + (size_t)n * D_INNER] = h[n];
  Sdt[((size_t)b * NCH + c) * D_INNER + d] = sdt;
}

// Pass B: serial prefix over NCH chunks; S[c] becomes the INITIAL state of
// chunk c. One thread per (b,n,d) = 131072, d-fast for coalescing.
__global__ __launch_bounds__(256) void scan_passB(
    float* __restrict__ S, const float* __restrict__ Sdt,
    const void* __restrict__ A_log, const int* __restrict__ flag) {
  const int bf = *flag;
  const int idx = blockIdx.x * 256 + threadIdx.x;
  const int d = idx & (D_INNER - 1);
  const int n = (idx >> 11) & 15;
  const int b = idx >> 15;
  const float al = bf ? ld1<true>(A_log, (size_t)d * 16 + n)
                      : ld1<false>(A_log, (size_t)d * 16 + n);
  const float a = -expf(al);
  float h = 0.f;
  for (int c = 0; c < NCH; ++c) {
    const size_t base = ((size_t)b * NCH + c);
    const size_t sidx = (base * 16 + n) * D_INNER + d;
    const float s = S[sidx];
    const float sdt = Sdt[base * D_INNER + d];
    const float p = __expf(a * sdt);
    S[sidx] = h;  // init for chunk c
    h = p * h + s;
  }
}

// Pass C: replay chunk from true init state; y = (sum_n h*C + D*x)*silu(z).
__global__ __launch_bounds__(256) void scan_passC(
    const unsigned short* __restrict__ xzb,
    const unsigned short* __restrict__ xcb,
    const unsigned short* __restrict__ dbl, const void* __restrict__ A_log,
    const void* __restrict__ Dp, const float* __restrict__ S,
    const int* __restrict__ flag, unsigned short* __restrict__ ybf) {
  __shared__ float Bsh[CL][16];  // 2 KiB
  __shared__ float Csh[CL][16];  // 2 KiB
  const int bf = *flag;
  const int gid = blockIdx.x * 256 + threadIdx.x;
  const int d = gid & (D_INNER - 1);
  const int c = (gid >> 11) & (NCH - 1);
  const int b = gid >> (11 + LOG_NCH);
  const size_t m0 = (size_t)b * SEQ + c * CL;
  // cooperative fill: B and C rows, 2+2 values per thread
  {
    const int tid = threadIdx.x;
#pragma unroll
    for (int k = 0; k < (CL * 16) / 256; ++k) {
      const int idx = tid + k * 256;
      const int t = idx >> 4, n = idx & 15;
      Bsh[t][n] = bf2f(dbl[(m0 + t) * 128 + 64 + n]);
      Csh[t][n] = bf2f(dbl[(m0 + t) * 128 + 80 + n]);
    }
  }
  float a[16], dev;
  load_a(A_log, bf, d, a, dev);
  const float Dv = bf ? ld1<true>(Dp, d) : ld1<false>(Dp, d);
  float h[16];
  const size_t sbase = (((size_t)b * NCH + c) * 16) * D_INNER + d;
#pragma unroll
  for (int n = 0; n < 16; ++n) h[n] = S[sbase + (size_t)n * D_INNER];
  __syncthreads();
  const bool trick = dev < 1e-3f;
  for (int t = 0; t < CL; ++t) {
    const size_t m = m0 + t;
    const float dtv = bf2f(xzb[m * 4096 + d]);
    const float xv = bf2f(xcb[m * 2048 + d]);
    const float dtx = dtv * xv;
    float y = 0.f;
    if (trick) {
      float pw[16];
      pow_tree(__expf(-dtv), pw);
      const f32x4 B0 = *(const f32x4*)&Bsh[t][0];
      const f32x4 B1 = *(const f32x4*)&Bsh[t][4];
      const f32x4 B2 = *(const f32x4*)&Bsh[t][8];
      const f32x4 B3 = *(const f32x4*)&Bsh[t][12];
      const f32x4 C0 = *(const f32x4*)&Csh[t][0];
      const f32x4 C1 = *(const f32x4*)&Csh[t][4];
      const f32x4 C2 = *(const f32x4*)&Csh[t][8];
      const f32x4 C3 = *(const f32x4*)&Csh[t][12];
#pragma unroll
      for (int j = 0; j < 4; ++j) {
        h[j] = fmaf(pw[j], h[j], B0[j] * dtx);
        y = fmaf(h[j], C0[j], y);
        h[4 + j] = fmaf(pw[4 + j], h[4 + j], B1[j] * dtx);
        y = fmaf(h[4 + j], C1[j], y);
        h[8 + j] = fmaf(pw[8 + j], h[8 + j], B2[j] * dtx);
        y = fmaf(h[8 + j], C2[j], y);
        h[12 + j] = fmaf(pw[12 + j], h[12 + j], B3[j] * dtx);
        y = fmaf(h[12 + j], C3[j], y);
      }
    } else {
#pragma unroll
      for (int n = 0; n < 16; ++n) {
        h[n] = fmaf(__expf(dtv * a[n]), h[n], Bsh[t][n] * dtx);
        y = fmaf(h[n], Csh[t][n], y);
      }
    }
    const float zv = bf2f(xzb[m * 4096 + 2048 + d]);
    const float yv = y + Dv * xv;
    ybf[m * 2048 + d] = f2bf(yv * (zv / (1.f + __expf(-zv))));
  }
}

// ---------------------------------------------------------------------------
extern "C" void kernel_launch(void* const* d_in, const int* in_sizes, int n_in,
                              void* d_out, int out_size, void* d_ws,
                              size_t ws_size, hipStream_t stream) {
  const void* x = d_in[0];
  const void* in_proj_w = d_in[1];
  const void* conv_w = d_in[2];
  const void* conv_b = d_in[3];
  const void* x_proj_w = d_in[4];
  const void* dt_proj_w = d_in[5];
  const void* dt_proj_b = d_in[6];
  const void* A_log = d_in[7];
  const void* D_param = d_in[8];
  const void* out_proj_w = d_in[9];

  // ws layout:
  // flag 256B | xzb 64MB | xcb 32MB (pre-conv hosts x_bf+ipw_bf) | dbl 2MB |
  // ybf 32MB | S 33.5MB (NCH=64; aliases k3part 16.8MB pre-scan) | Sdt 2MB |
  // opw 4MB | xpw_pad 512KB | dtw 256KB
  char* wsb = (char*)d_ws;
  int* flag = (int*)wsb;
  unsigned short* xzb = (unsigned short*)(wsb + 256);
  unsigned short* xcb = xzb + (size_t)ML * 4096;
  unsigned short* dbl = xcb + (size_t)ML * 2048;
  unsigned short* ybf = dbl + (size_t)ML * 128;
  float* S = (float*)(ybf + (size_t)ML * 2048);
  float* Sdt = S + (size_t)BATCH * NCH * D_INNER * 16;
  unsigned short* opw_bf =
      (unsigned short*)(Sdt + (size_t)BATCH * NCH * D_INNER);
  unsigned short* xpw_pad = opw_bf + (size_t)1024 * 2048;
  unsigned short* dtw_bf = xpw_pad + (size_t)128 * 2048;
  unsigned short* x_bf = xcb;                        // dead after K1
  unsigned short* ipw_bf = xcb + (size_t)ML * 1024;  // dead after K1
  float* k3part = S;  // 4 x (ML x 128) f32 = 16.78 MB; dead before scans

  // fused conversions + inline dtype detection (one dispatch)
  cvt_all_kernel<<<CVT_E4 / 1024, 256, 0, stream>>>(
      x, in_proj_w, out_proj_w, dt_proj_w, x_proj_w, x_bf, ipw_bf, opw_bf,
      dtw_bf, xpw_pad, flag);
  // K1: xz = x @ in_proj_w^T (M=8192,N=4096,K=1024) -> xzb bf16
  gemm256_k1<<<dim3(512), 512, 0, stream>>>(x_bf, ipw_bf, xzb);
  // K2: causal depthwise conv + SiLU -> xcb bf16 (x_bf/ipw_bf now dead)
  conv_silu_kernel<<<(ML * D_INNER) / 1024, 256, 0, stream>>>(
      xzb, conv_w, conv_b, xcb, flag);
  // K3: dbl = xc @ x_proj_w^T (M=8192, N=128(pad), K=2048), split-K x4 ->
  // f32 partials in S region, then reduce+bf16.
  {
    dim3 g(1, ML / 128, 4);
    gemm_mfma<3, 3><<<g, 256, 0, stream>>>(xcb, 2048, xpw_pad, 2048, k3part,
                                           128, 512, nullptr, flag);
  }
  reduceK3_kernel<<<(ML * 128) / 1024, 256, 0, stream>>>(k3part, dbl);
  // K4: dt = softplus(dbl[:,:64] @ dt_proj_w^T + b) -> xzb x-half (ldc=4096)
  dt_gemm_kernel<<<dim3(16, 64), 256, 0, stream>>>(dbl, dtw_bf, xzb,
                                                   dt_proj_b, flag);
  // K5: chunked scan, NCH=64, LDS-staged f32 B/C rows (R12)
  scan_passA<<<(BATCH * NCH * D_INNER) / 256, 256, 0, stream>>>(
      xzb, xcb, dbl, A_log, flag, S, Sdt);
  scan_passB<<<(BATCH * D_INNER * 16) / 256, 256, 0, stream>>>(S, Sdt, A_log,
                                                               flag);
  scan_passC<<<(BATCH * NCH * D_INNER) / 256, 256, 0, stream>>>(
      xzb, xcb, dbl, A_log, D_param, S, flag, ybf);
  // K6: out = y @ out_proj_w^T (M=8192,N=1024,K=2048), out dtype per flag
  gemm256x128_k6<<<dim3(256), 512, 0, stream>>>(ybf, opw_bf, d_out, flag);
}

// Round 13
// 402.936 us; speedup vs baseline: 1.1576x; 1.0457x over previous
//
#include <hip/hip_runtime.h>
#include <hip/hip_bf16.h>
#include <math.h>

#define D_MODEL 1024
#define D_STATE 16
#define D_CONV 4
#define D_INNER 2048
#define DT_RANK 64
#define BATCH 4
#define SEQ 2048
#define ML (BATCH * SEQ)  // 8192 rows
#define NCH 64            // scan chunks per sequence
#define LOG_NCH 6
#define CL (SEQ / NCH)    // 32 steps per chunk

typedef __attribute__((ext_vector_type(8))) short short8;
typedef __attribute__((ext_vector_type(8))) unsigned short u16x8;
typedef __attribute__((ext_vector_type(4))) float f32x4;

// ---------------------------------------------------------------------------
// dtype helpers: inputs may be fp32 (expected) or bf16 (runtime-detected).
// ---------------------------------------------------------------------------
__device__ __forceinline__ float bf2f(unsigned short u) {
  union { unsigned int i; float f; } v;
  v.i = ((unsigned int)u) << 16;
  return v.f;
}
__device__ __forceinline__ unsigned short f2bf(float f) {
  union { float f; unsigned int i; } u;
  u.f = f;
  unsigned int r = u.i + 0x7fffu + ((u.i >> 16) & 1u);  // RNE
  return (unsigned short)(r >> 16);
}
// packed f32x2 -> bf16x2 (v_cvt_pk_bf16_f32 on gfx950); low 16 = a, high = b
__device__ __forceinline__ unsigned int f2bf_pk(float a, float b) {
  union { __hip_bfloat162 h; unsigned int u; } cv;
  cv.h = __float22bfloat162_rn(make_float2(a, b));
  return cv.u;
}
template <bool BF>
__device__ __forceinline__ float ld1(const void* p, size_t i) {
  if constexpr (BF) return bf2f(((const unsigned short*)p)[i]);
  else return ((const float*)p)[i];
}
template <bool BF>
__device__ __forceinline__ void ld4(const void* p, size_t i, float o[4]) {
  if constexpr (BF) {
    ushort4 v = *(const ushort4*)((const unsigned short*)p + i);
    o[0] = bf2f(v.x); o[1] = bf2f(v.y); o[2] = bf2f(v.z); o[3] = bf2f(v.w);
  } else {
    float4 v = *(const float4*)((const float*)p + i);
    o[0] = v.x; o[1] = v.y; o[2] = v.z; o[3] = v.w;
  }
}

// async global->LDS, 16 B per lane; lds base must be wave-uniform.
__device__ __forceinline__ void gl_lds16(const unsigned short* g,
                                         unsigned short* l) {
  __builtin_amdgcn_global_load_lds(
      (const __attribute__((address_space(1))) void*)g,
      (__attribute__((address_space(3))) void*)l, 16, 0, 0);
}

// ---------------------------------------------------------------------------
// Fused conversion of all weights/x to bf16 (one dispatch). Dtype detection
// (flag=1 means bf16 inputs) folded in; block 0 publishes flag[0].
// ---------------------------------------------------------------------------
#define CVT_N0 (ML * 1024)
#define CVT_N1 (4096 * 1024)
#define CVT_N2 (1024 * 2048)
#define CVT_N3 (2048 * 64)
#define CVT_N4 (128 * 2048)
#define CVT_E0 CVT_N0
#define CVT_E1 (CVT_E0 + CVT_N1)
#define CVT_E2 (CVT_E1 + CVT_N2)
#define CVT_E3 (CVT_E2 + CVT_N3)
#define CVT_E4 (CVT_E3 + CVT_N4)

__device__ __forceinline__ void cvt4(const void* in, size_t i,
                                     unsigned short* out, size_t o, int bf) {
  if (bf) {
    *(ushort4*)(out + o) = *(const ushort4*)((const unsigned short*)in + i);
  } else {
    float4 f = *(const float4*)((const float*)in + i);
    uint2 v;
    v.x = f2bf_pk(f.x, f.y);
    v.y = f2bf_pk(f.z, f.w);
    *(uint2*)(out + o) = v;
  }
}

__global__ __launch_bounds__(256) void cvt_all_kernel(
    const void* __restrict__ x, const void* __restrict__ ipw,
    const void* __restrict__ opw, const void* __restrict__ dtw,
    const void* __restrict__ xpw, unsigned short* __restrict__ x_bf,
    unsigned short* __restrict__ ipw_bf, unsigned short* __restrict__ opw_bf,
    unsigned short* __restrict__ dtw_bf, unsigned short* __restrict__ xpw_pad,
    int* __restrict__ flag) {
  // inline dtype sniff (same logic as the old detect_kernel)
  __shared__ int cnt;
  if (threadIdx.x == 0) cnt = 0;
  __syncthreads();
  {
    const unsigned int wv = ((const unsigned int*)x)[threadIdx.x];
    const unsigned int e = (wv >> 7) & 0xffu;
    if (e < 100u || e > 145u) atomicAdd(&cnt, 1);
  }
  __syncthreads();
  const int bf = (cnt < 32) ? 1 : 0;
  if (blockIdx.x == 0 && threadIdx.x == 0) flag[0] = bf;

  const size_t g = (size_t)(blockIdx.x * 256 + threadIdx.x) * 4;
  if (g < CVT_E0) {
    cvt4(x, g, x_bf, g, bf);
  } else if (g < CVT_E1) {
    const size_t i = g - CVT_E0;
    cvt4(ipw, i, ipw_bf, i, bf);
  } else if (g < CVT_E2) {
    const size_t i = g - CVT_E1;
    cvt4(opw, i, opw_bf, i, bf);
  } else if (g < CVT_E3) {
    const size_t i = g - CVT_E2;
    cvt4(dtw, i, dtw_bf, i, bf);
  } else if (g < CVT_E4) {
    const size_t i = g - CVT_E3;
    const int row = (int)(i >> 11);
    if (row < 96) {
      cvt4(xpw, i, xpw_pad, i, bf);
    } else {
      ushort4 z = {0, 0, 0, 0};
      *(ushort4*)(xpw_pad + i) = z;
    }
  }
}

// ---------------------------------------------------------------------------
// K1 GEMM, 256x256 8-phase schedule (T1+T2+T3+T4+T5, m201 template):
//   C[8192,4096] bf16 = A[8192,1024] * B[4096,1024]^T, all bf16.
// R2 result: 82.6 us, 834 TF, bank-conflict 0. Left untouched.
// ---------------------------------------------------------------------------
#define K1_LDA 1024
#define K1_NT 16  // K/64

#define K1_STG(srcbase, lds, t_, h_)                                       \
  {                                                                        \
    const unsigned short* s_ =                                             \
        (srcbase) + (size_t)(h_) * (128 * K1_LDA) + (size_t)(t_) * 64;     \
    unsigned short* d_ = (lds) + (((t_) & 1) * 2 + (h_)) * 8192 + w * 512; \
    gl_lds16(s_, d_);                                                      \
    gl_lds16(s_ + 64 * K1_LDA, d_ + 4096);                                 \
  }

__global__ __launch_bounds__(512, 2) void gemm256_k1(
    const unsigned short* __restrict__ A,  // 8192 x 1024 bf16
    const unsigned short* __restrict__ B,  // 4096 x 1024 bf16 (row = n)
    unsigned short* __restrict__ C) {      // 8192 x 4096 bf16
  __shared__ unsigned short As[32768];  // [buf][half][128][64]
  __shared__ unsigned short Bs[32768];
  const int tid = threadIdx.x;
  const int l = tid & 63, w = tid >> 6;
  // XCD-bijective swizzle: 512 wgs, 8 XCDs, 64 contiguous per XCD.
  const int bid = blockIdx.x;
  const int swz = (bid & 7) * 64 + (bid >> 3);
  const int m0 = (swz >> 4) * 256, n0 = (swz & 15) * 256;
  // staging per-lane source (pre-swizzled chunk; low3(row) invariant under
  // +64/+128 row offsets, so one chunk index serves all halves/calls)
  const int row0 = tid >> 3;  // 0..63 within a stage call
  const int c0 = (tid & 7) ^ (row0 & 7);
  const unsigned short* aSrc = A + (size_t)(m0 + row0) * K1_LDA + c0 * 8;
  const unsigned short* bSrc = B + (size_t)(n0 + row0) * K1_LDA + c0 * 8;
  // fragment coords
  const int q = l >> 4, mr = l & 15;
  const int wm = w >> 2, wn = w & 3;

  // prologue: tile0 (4 halves) then tile1 {B.h0,B.h1,A.h0}; wait so tile0's
  // 8 loads (the oldest) are landed, 3 half-tiles outstanding.
  K1_STG(aSrc, As, 0, 0);
  K1_STG(aSrc, As, 0, 1);
  K1_STG(bSrc, Bs, 0, 0);
  K1_STG(bSrc, Bs, 0, 1);
  K1_STG(bSrc, Bs, 1, 0);
  K1_STG(bSrc, Bs, 1, 1);
  K1_STG(aSrc, As, 1, 0);
  asm volatile("s_waitcnt vmcnt(6)" ::: "memory");
  asm volatile("s_barrier" ::: "memory");

  f32x4 acc[8][4] = {};
  for (int t = 0; t < K1_NT; ++t) {
    const int tb = (t & 1) * 2;
    // ---- P1 ds_reads: all B frags (8) + A frags mi{0,1} (4) = 12 reads
    short8 bfr[4][2];
#pragma unroll
    for (int ni = 0; ni < 4; ++ni)
#pragma unroll
      for (int kk = 0; kk < 2; ++kk) {
        const int r = (wn & 1) * 64 + ni * 16 + mr;
        const int c = kk * 4 + q;
        bfr[ni][kk] = *(const short8*)&Bs[(tb + (wn >> 1)) * 8192 + r * 64 +
                                          ((c ^ (r & 7)) * 8)];
      }
#pragma unroll
    for (int p = 0; p < 4; ++p) {
      short8 af[2][2];
#pragma unroll
      for (int i = 0; i < 2; ++i)
#pragma unroll
        for (int kk = 0; kk < 2; ++kk) {
          const int r = (2 * p + i) * 16 + mr;
          const int c = kk * 4 + q;
          af[i][kk] = *(const short8*)&As[(tb + wm) * 8192 + r * 64 +
                                          ((c ^ (r & 7)) * 8)];
        }
      // stage one half-tile (issued after this phase's ds_reads)
      if (p == 0) {
        if (t + 1 < K1_NT) K1_STG(aSrc, As, t + 1, 1);
      } else if (p == 1) {
        if (t + 2 < K1_NT) K1_STG(bSrc, Bs, t + 2, 0);
      } else if (p == 2) {
        if (t + 2 < K1_NT) K1_STG(bSrc, Bs, t + 2, 1);
      } else {
        if (t + 2 < K1_NT) K1_STG(aSrc, As, t + 2, 0);
      }
      asm volatile("s_barrier" ::: "memory");
      __builtin_amdgcn_s_setprio(1);
#pragma unroll
      for (int i = 0; i < 2; ++i)
#pragma unroll
        for (int ni = 0; ni < 4; ++ni)
#pragma unroll
          for (int kk = 0; kk < 2; ++kk)
            acc[2 * p + i][ni] = __builtin_amdgcn_mfma_f32_16x16x32_bf16(
                af[i][kk], bfr[ni][kk], acc[2 * p + i][ni], 0, 0, 0);
      __builtin_amdgcn_s_setprio(0);
      if (p == 3) {
        if (t + 2 < K1_NT) {
          asm volatile("s_waitcnt vmcnt(6)" ::: "memory");
        } else {
          asm volatile("s_waitcnt vmcnt(0)" ::: "memory");
        }
      }
      asm volatile("s_barrier" ::: "memory");
    }
  }
  // epilogue: C/D layout col=lane&15, row=(lane>>4)*4+reg  [m89/m91]
#pragma unroll
  for (int mi = 0; mi < 8; ++mi) {
#pragma unroll
    for (int ni = 0; ni < 4; ++ni) {
      const int row = m0 + wm * 128 + mi * 16 + q * 4;
      const int col = n0 + wn * 64 + ni * 16 + mr;
      const size_t off0 = (size_t)row * 4096 + col;
      const unsigned int p01 = f2bf_pk(acc[mi][ni][0], acc[mi][ni][1]);
      const unsigned int p23 = f2bf_pk(acc[mi][ni][2], acc[mi][ni][3]);
      C[off0] = (unsigned short)p01;
      C[off0 + 4096] = (unsigned short)(p01 >> 16);
      C[off0 + 2 * 4096] = (unsigned short)p23;
      C[off0 + 3 * 4096] = (unsigned short)(p23 >> 16);
    }
  }
}

// ---------------------------------------------------------------------------
// K6: out = y @ out_proj_w^T (M=8192, N=1024, K=2048), K1's schedule at
// BM=256 BN=128 BK=64. R4: verified. Untouched.
// ---------------------------------------------------------------------------
#define K6_LDA 2048
#define K6_NT 32  // K/64

#define K6_STGA(t_, h_)                                                 \
  {                                                                     \
    const unsigned short* s_ =                                          \
        aSrc + (size_t)(h_) * (128 * K6_LDA) + (size_t)(t_) * 64;       \
    unsigned short* d_ = As + (((t_) & 1) * 2 + (h_)) * 8192 + w * 512; \
    gl_lds16(s_, d_);                                                   \
    gl_lds16(s_ + 64 * K6_LDA, d_ + 4096);                              \
  }
#define K6_STGB(t_)                                            \
  {                                                            \
    const unsigned short* s_ = bSrc + (size_t)(t_) * 64;       \
    unsigned short* d_ = Bs6 + ((t_) & 1) * 8192 + w * 512;    \
    gl_lds16(s_, d_);                                          \
    gl_lds16(s_ + 64 * K6_LDA, d_ + 4096);                     \
  }

__global__ __launch_bounds__(512, 2) void gemm256x128_k6(
    const unsigned short* __restrict__ A,  // ybf 8192 x 2048 bf16
    const unsigned short* __restrict__ B,  // opw 1024 x 2048 bf16 (row = n)
    void* __restrict__ C,                  // out 8192 x 1024 (f32 or bf16)
    const int* __restrict__ flag) {
  __shared__ unsigned short As[32768];   // [buf][half][128][64]
  __shared__ unsigned short Bs6[16384];  // [buf][128][64]
  const int tid = threadIdx.x;
  const int l = tid & 63, w = tid >> 6;
  // XCD-bijective swizzle: 256 wgs, 8 XCDs, 32 contiguous per XCD.
  const int bid = blockIdx.x;
  const int swz = (bid & 7) * 32 + (bid >> 3);
  const int n0 = (swz & 7) * 128, m0 = (swz >> 3) * 256;
  const int row0 = tid >> 3;  // 0..63 within a stage call
  const int c0 = (tid & 7) ^ (row0 & 7);
  const unsigned short* aSrc = A + (size_t)(m0 + row0) * K6_LDA + c0 * 8;
  const unsigned short* bSrc = B + (size_t)(n0 + row0) * K6_LDA + c0 * 8;
  // fragment coords
  const int q = l >> 4, mr = l & 15;
  const int wm = w >> 2, wn = w & 3;

  // prologue: tile0 {A.h0,A.h1,B}, tile1 {B, A.h0}; vmcnt(4) -> tile0 landed,
  // {B(1), A.h0(1)} (4 loads) in flight.
  K6_STGA(0, 0);
  K6_STGA(0, 1);
  K6_STGB(0);
  K6_STGB(1);
  K6_STGA(1, 0);
  asm volatile("s_waitcnt vmcnt(4)" ::: "memory");
  asm volatile("s_barrier" ::: "memory");

  f32x4 acc[8][2] = {};
  for (int t = 0; t < K6_NT; ++t) {
    const int tb = (t & 1) * 2;
    // B frags for this tile (4 reads)
    short8 bfr[2][2];
#pragma unroll
    for (int ni = 0; ni < 2; ++ni)
#pragma unroll
      for (int kk = 0; kk < 2; ++kk) {
        const int r = wn * 32 + ni * 16 + mr;
        const int c = kk * 4 + q;
        bfr[ni][kk] = *(const short8*)&Bs6[(t & 1) * 8192 + r * 64 +
                                           ((c ^ (r & 7)) * 8)];
      }
#pragma unroll
    for (int p = 0; p < 4; ++p) {
      short8 af[2][2];
#pragma unroll
      for (int i = 0; i < 2; ++i)
#pragma unroll
        for (int kk = 0; kk < 2; ++kk) {
          const int r = (2 * p + i) * 16 + mr;
          const int c = kk * 4 + q;
          af[i][kk] = *(const short8*)&As[(tb + wm) * 8192 + r * 64 +
                                          ((c ^ (r & 7)) * 8)];
        }
      // stage schedule
      if (p == 0) {
        if (t + 1 < K6_NT) K6_STGA(t + 1, 1);
      } else if (p == 1) {
        if (t + 2 < K6_NT) K6_STGB(t + 2);
      } else if (p == 3) {
        if (t + 2 < K6_NT) K6_STGA(t + 2, 0);
      }
      asm volatile("s_barrier" ::: "memory");
      __builtin_amdgcn_s_setprio(1);
#pragma unroll
      for (int i = 0; i < 2; ++i)
#pragma unroll
        for (int ni = 0; ni < 2; ++ni)
#pragma unroll
          for (int kk = 0; kk < 2; ++kk)
            acc[2 * p + i][ni] = __builtin_amdgcn_mfma_f32_16x16x32_bf16(
                af[i][kk], bfr[ni][kk], acc[2 * p + i][ni], 0, 0, 0);
      __builtin_amdgcn_s_setprio(0);
      if (p == 3) {
        if (t + 2 < K6_NT) {
          asm volatile("s_waitcnt vmcnt(4)" ::: "memory");
        } else {
          asm volatile("s_waitcnt vmcnt(0)" ::: "memory");
        }
      }
      asm volatile("s_barrier" ::: "memory");
    }
  }
  // epilogue: C/D layout col=lane&15, row=(lane>>4)*4+reg  [m89/m91]
  const int bf = *flag;
#pragma unroll
  for (int mi = 0; mi < 8; ++mi) {
#pragma unroll
    for (int ni = 0; ni < 2; ++ni) {
      const int row = m0 + wm * 128 + mi * 16 + q * 4;
      const int col = n0 + wn * 32 + ni * 16 + mr;
      const size_t off0 = (size_t)row * 1024 + col;
      if (bf) {
        const unsigned int p01 = f2bf_pk(acc[mi][ni][0], acc[mi][ni][1]);
        const unsigned int p23 = f2bf_pk(acc[mi][ni][2], acc[mi][ni][3]);
        unsigned short* C16 = (unsigned short*)C;
        C16[off0] = (unsigned short)p01;
        C16[off0 + 1024] = (unsigned short)(p01 >> 16);
        C16[off0 + 2 * 1024] = (unsigned short)p23;
        C16[off0 + 3 * 1024] = (unsigned short)(p23 >> 16);
      } else {
        float* Cf = (float*)C;
#pragma unroll
        for (int j = 0; j < 4; ++j)
          Cf[off0 + (size_t)j * 1024] = acc[mi][ni][j];
      }
    }
  }
}

// ---------------------------------------------------------------------------
// K3: split-K x4 + reduce. 128x128 tile, BK=32, 4 waves, EPI3 split-K
// partials. Untouched.
// ---------------------------------------------------------------------------
template <int EPI, int TAG>
__global__ __launch_bounds__(256) void gemm_mfma(
    const unsigned short* __restrict__ Ain, int lda,
    const unsigned short* __restrict__ Bin, int ldb, void* __restrict__ C,
    int ldc, int K, const void* __restrict__ bias,
    const int* __restrict__ flag) {
  __shared__ unsigned short As[128 * 32];
  __shared__ unsigned short Bs[128 * 32];
  const unsigned short* A = Ain;
  const unsigned short* B = Bin;
  if (EPI == 3) {  // split-K slice
    A += (size_t)blockIdx.z * 512;
    B += (size_t)blockIdx.z * 512;
  }
  const int tid = threadIdx.x;
  const int l = tid & 63, w = tid >> 6;
  const int bm = blockIdx.y * 128;
  const int bn = blockIdx.x * 128;
  // staging: lane l of wave w covers row (w*16 + l/4); swizzled k-chunk.
  const int r0 = w * 16 + (l >> 2);
  const int cc = (((l & 3) ^ ((l >> 2) & 3) ^ ((l >> 4) & 3))) * 8;
  const unsigned short* Ap0 = A + (size_t)(bm + r0) * lda + cc;
  const unsigned short* Ap1 = A + (size_t)(bm + r0 + 64) * lda + cc;
  const unsigned short* Bp0 = B + (size_t)(bn + r0) * ldb + cc;
  const unsigned short* Bp1 = B + (size_t)(bn + r0 + 64) * ldb + cc;
  // fragment coords
  const int q = l >> 4, mr = l & 15;
  const int wm = w >> 1, wn = w & 1;
  const int slot = (q ^ (mr & 3) ^ (mr >> 2)) * 8;  // swizzled k-slot
  f32x4 acc[4][4] = {};
  for (int k0 = 0; k0 < K; k0 += 32) {
    gl_lds16(Ap0 + k0, As + w * 512);
    gl_lds16(Ap1 + k0, As + 2048 + w * 512);
    gl_lds16(Bp0 + k0, Bs + w * 512);
    gl_lds16(Bp1 + k0, Bs + 2048 + w * 512);
    __syncthreads();  // drains vmcnt (global_load_lds)
    short8 af[4], bfr[4];
#pragma unroll
    for (int mi = 0; mi < 4; ++mi)
      af[mi] = *(const short8*)&As[(wm * 64 + mi * 16 + mr) * 32 + slot];
#pragma unroll
    for (int ni = 0; ni < 4; ++ni)
      bfr[ni] = *(const short8*)&Bs[(wn * 64 + ni * 16 + mr) * 32 + slot];
#pragma unroll
    for (int mi = 0; mi < 4; ++mi)
#pragma unroll
      for (int ni = 0; ni < 4; ++ni)
        acc[mi][ni] = __builtin_amdgcn_mfma_f32_16x16x32_bf16(
            af[mi], bfr[ni], acc[mi][ni], 0, 0, 0);
    __syncthreads();
  }
  // epilogue: C/D layout col=lane&15, row=(lane>>4)*4+reg  [m89/m91]
  float* Cp3 = (EPI == 3)
                   ? ((float*)C + (size_t)blockIdx.z * ML * 128)
                   : (float*)C;
#pragma unroll
  for (int mi = 0; mi < 4; ++mi) {
#pragma unroll
    for (int ni = 0; ni < 4; ++ni) {
      const int row = bm + wm * 64 + mi * 16 + q * 4;
      const int col = bn + wn * 64 + ni * 16 + mr;
      const size_t off0 = (size_t)row * ldc + col;
      if (EPI == 3) {
#pragma unroll
        for (int j = 0; j < 4; ++j)
          Cp3[off0 + (size_t)j * ldc] = acc[mi][ni][j];
      } else {
        const unsigned int p01 = f2bf_pk(acc[mi][ni][0], acc[mi][ni][1]);
        const unsigned int p23 = f2bf_pk(acc[mi][ni][2], acc[mi][ni][3]);
        unsigned short* C16 = (unsigned short*)C;
        C16[off0] = (unsigned short)p01;
        C16[off0 + ldc] = (unsigned short)(p01 >> 16);
        C16[off0 + 2 * (size_t)ldc] = (unsigned short)p23;
        C16[off0 + 3 * (size_t)ldc] = (unsigned short)(p23 >> 16);
      }
    }
  }
}

// Split-K reduce: dbl = bf16(sum of 4 f32 partials). 1M elems, 4/thread.
__global__ __launch_bounds__(256) void reduceK3_kernel(
    const float* __restrict__ part, unsigned short* __restrict__ dbl) {
  const size_t i = (size_t)(blockIdx.x * 256 + threadIdx.x) * 4;
  const size_t st = (size_t)ML * 128;
  float4 a = *(const float4*)(part + i);
  float4 b = *(const float4*)(part + st + i);
  float4 c = *(const float4*)(part + 2 * st + i);
  float4 d = *(const float4*)(part + 3 * st + i);
  uint2 v;
  v.x = f2bf_pk(a.x + b.x + c.x + d.x, a.y + b.y + c.y + d.y);
  v.y = f2bf_pk(a.z + b.z + c.z + d.z, a.w + b.w + c.w + d.w);
  *(uint2*)(dbl + i) = v;
}

// ---------------------------------------------------------------------------
// K4 (R11): dt = softplus(dbl[:,0:64] @ dtw^T + b) -> xzb x-half (ldc=4096).
// Grid (16 n x 64 m) = 1024 wgs = 4 blocks/CU = 16 waves/CU; single-shot
// tile, latency hidden by inter-block TLP. R11: verified (left top-5).
// ---------------------------------------------------------------------------
__global__ __launch_bounds__(256) void dt_gemm_kernel(
    const unsigned short* __restrict__ Adbl,  // (ML,128) bf16, cols 0:64 used
    const unsigned short* __restrict__ Bw,    // (2048,64) bf16
    unsigned short* __restrict__ Cdt,         // xzb base; ldc=4096, x-half
    const void* __restrict__ bias, const int* __restrict__ flag) {
  __shared__ unsigned short Bs[128 * 64];  // 16 KiB
  __shared__ unsigned short As[128 * 64];  // 16 KiB
  const int tid = threadIdx.x;
  const int l = tid & 63, w = tid >> 6;
  const int bn = blockIdx.x * 128;  // n-tile
  const int mg = blockIdx.y * 128;  // m-tile
  // staging: per call, 256 thr cover 32 rows x 64 cols (128B rows);
  // pre-swizzled source chunk (row&7 invariant under +32 row offsets).
  const int srow = tid >> 3;                    // 0..31
  const int sc = ((tid & 7) ^ (srow & 7)) * 8;  // chunk involution
  const unsigned short* aSrc = Adbl + (size_t)(mg + srow) * 128 + sc;
  const unsigned short* bSrc = Bw + (size_t)(bn + srow) * 64 + sc;
#pragma unroll
  for (int i = 0; i < 4; ++i)
    gl_lds16(bSrc + (size_t)i * 32 * 64, Bs + i * 2048 + w * 512);
#pragma unroll
  for (int i = 0; i < 4; ++i)
    gl_lds16(aSrc + (size_t)i * 32 * 128, As + i * 2048 + w * 512);
  asm volatile("s_waitcnt vmcnt(0)" ::: "memory");
  asm volatile("s_barrier" ::: "memory");
  // fragment coords: 4 waves = 2M x 2N, wave tile 64x64
  const int q = l >> 4, mr = l & 15;
  const int wm = w >> 1, wn = w & 1;
  const int bf = *flag;
  short8 af[4][2], bfr[4][2];
#pragma unroll
  for (int ni = 0; ni < 4; ++ni)
#pragma unroll
    for (int kk = 0; kk < 2; ++kk) {
      const int r = wn * 64 + ni * 16 + mr;
      const int c = kk * 4 + q;
      bfr[ni][kk] = *(const short8*)&Bs[r * 64 + ((c ^ (r & 7)) * 8)];
    }
#pragma unroll
  for (int mi = 0; mi < 4; ++mi)
#pragma unroll
    for (int kk = 0; kk < 2; ++kk) {
      const int r = wm * 64 + mi * 16 + mr;
      const int c = kk * 4 + q;
      af[mi][kk] = *(const short8*)&As[r * 64 + ((c ^ (r & 7)) * 8)];
    }
  f32x4 acc[4][4] = {};
#pragma unroll
  for (int mi = 0; mi < 4; ++mi)
#pragma unroll
    for (int ni = 0; ni < 4; ++ni)
#pragma unroll
      for (int kk = 0; kk < 2; ++kk)
        acc[mi][ni] = __builtin_amdgcn_mfma_f32_16x16x32_bf16(
            af[mi][kk], bfr[ni][kk], acc[mi][ni], 0, 0, 0);
  // epilogue: softplus + bf16 store (C/D layout m89/m91)
#pragma unroll
  for (int mi = 0; mi < 4; ++mi) {
#pragma unroll
    for (int ni = 0; ni < 4; ++ni) {
      const int row = mg + wm * 64 + mi * 16 + q * 4;
      const int col = bn + wn * 64 + ni * 16 + mr;
      const size_t off0 = (size_t)row * 4096 + col;
      const float bv = bf ? ld1<true>(bias, col) : ld1<false>(bias, col);
      float v[4];
#pragma unroll
      for (int j = 0; j < 4; ++j) {
        const float t = acc[mi][ni][j] + bv;
        v[j] = fmaxf(t, 0.f) + __logf(1.f + __expf(-fabsf(t)));
      }
      const unsigned int p01 = f2bf_pk(v[0], v[1]);
      const unsigned int p23 = f2bf_pk(v[2], v[3]);
      Cdt[off0] = (unsigned short)p01;
      Cdt[off0 + 4096] = (unsigned short)(p01 >> 16);
      Cdt[off0 + 2 * 4096] = (unsigned short)p23;
      Cdt[off0 + 3 * 4096] = (unsigned short)(p23 >> 16);
    }
  }
}

// ---------------------------------------------------------------------------
// Depthwise causal conv (width 4) + bias + SiLU, 4 channels per thread.
// xzb: (ML,4096) bf16; x part = cols [0,2048). Output xcb (ML,2048) bf16.
// ---------------------------------------------------------------------------
__global__ __launch_bounds__(256) void conv_silu_kernel(
    const unsigned short* __restrict__ xzb, const void* __restrict__ cw,
    const void* __restrict__ cb, unsigned short* __restrict__ xcb,
    const int* __restrict__ flag) {
  const int bf = *flag;
  const int e = (blockIdx.x * 256 + threadIdx.x) * 4;  // over ML*D_INNER
  const int d = e & (D_INNER - 1);
  const int bl = e >> 11;
  const int l = bl & (SEQ - 1);
  const size_t base = (size_t)bl * 4096 + d;
  float x0[4], x1[4] = {}, x2[4] = {}, x3[4] = {};
  ld4<true>(xzb, base, x0);
  if (l >= 1) ld4<true>(xzb, base - 4096, x1);
  if (l >= 2) ld4<true>(xzb, base - 2 * 4096, x2);
  if (l >= 3) ld4<true>(xzb, base - 3 * 4096, x3);
  float r[4];
#pragma unroll
  for (int i = 0; i < 4; ++i) {
    float w[4];
    if (bf) ld4<true>(cw, (size_t)(d + i) * 4, w);
    else ld4<false>(cw, (size_t)(d + i) * 4, w);
    const float bias = bf ? ld1<true>(cb, d + i) : ld1<false>(cb, d + i);
    float acc = bias + w[3] * x0[i] + w[2] * x1[i] + w[1] * x2[i] + w[0] * x3[i];
    r[i] = acc / (1.f + __expf(-acc));  // silu
  }
  uint2 o;
  o.x = f2bf_pk(r[0], r[1]);
  o.y = f2bf_pk(r[2], r[3]);
  *(uint2*)(xcb + e) = o;
}

// ---------------------------------------------------------------------------
// Chunked selective scan, thread-per-channel, h[16] in VGPRs.
// R12: LDS-staged f32 B/C rows (block-shared). R13: register prefetch
// (depth 1) of the serial loop's dtv/xv/zv loads — the loop is
// load-latency-bound (R10: passC 13.8% HBM, high stall; VALU floor ~12us);
// issuing step t+1's loads before step t's exp/fma chain covers most of the
// ~200cy L2 latency. tn = min(t+1, CL-1): branchless, last iter re-loads.
// Bit-identical arithmetic. NCH=64 (CL=32). S layout [b][c][n][d].
// ---------------------------------------------------------------------------
__device__ __forceinline__ void load_a(const void* A_log, int bf, int d,
                                       float a[16], float& dev) {
  float t[4];
#pragma unroll
  for (int k = 0; k < 4; ++k) {
    if (bf) ld4<true>(A_log, (size_t)d * 16 + k * 4, t);
    else ld4<false>(A_log, (size_t)d * 16 + k * 4, t);
#pragma unroll
    for (int j = 0; j < 4; ++j) a[k * 4 + j] = -expf(t[j]);
  }
  dev = 0.f;
#pragma unroll
  for (int n = 0; n < 16; ++n) dev = fmaxf(dev, fabsf(a[n] + (float)(n + 1)));
}

// powers pw[n] = e1^(n+1), log-depth tree (max dep ~5)
__device__ __forceinline__ void pow_tree(float e1, float pw[16]) {
  const float e2 = e1 * e1;
  const float e3 = e2 * e1;
  const float e4 = e2 * e2;
  pw[0] = e1; pw[1] = e2; pw[2] = e3; pw[3] = e4;
  pw[4] = e4 * e1; pw[5] = e4 * e2; pw[6] = e4 * e3; pw[7] = e4 * e4;
  const float e8 = pw[7];
  pw[8] = e8 * e1; pw[9] = e8 * e2; pw[10] = e8 * e3; pw[11] = e8 * e4;
  pw[12] = e8 * pw[4]; pw[13] = e8 * pw[5]; pw[14] = e8 * pw[6];
  pw[15] = e8 * e8;
}

// Pass A: from h=0, chunk-final state S[b][c][n][d]; sdt per (b,c,d).
__global__ __launch_bounds__(256) void scan_passA(
    const unsigned short* __restrict__ xzb,
    const unsigned short* __restrict__ xcb,
    const unsigned short* __restrict__ dbl, const void* __restrict__ A_log,
    const int* __restrict__ flag, float* __restrict__ S,
    float* __restrict__ Sdt) {
  __shared__ float Bsh[CL][16];  // 2 KiB, block-shared B rows (f32)
  const int bf = *flag;
  const int gid = blockIdx.x * 256 + threadIdx.x;
  const int d = gid & (D_INNER - 1);
  const int c = (gid >> 11) & (NCH - 1);
  const int b = gid >> (11 + LOG_NCH);
  const size_t m0 = (size_t)b * SEQ + c * CL;
  // cooperative fill: CL*16 = 512 values, 2 per thread
  {
    const int tid = threadIdx.x;
#pragma unroll
    for (int k = 0; k < (CL * 16) / 256; ++k) {
      const int idx = tid + k * 256;
      const int t = idx >> 4, n = idx & 15;
      Bsh[t][n] = bf2f(dbl[(m0 + t) * 128 + 64 + n]);
    }
  }
  float a[16], dev;
  load_a(A_log, bf, d, a, dev);
  __syncthreads();
  float h[16] = {};
  float sdt = 0.f;
  // R13: depth-1 register prefetch of the serial loop's loads
  float dtv = bf2f(xzb[m0 * 4096 + d]);
  float xv = bf2f(xcb[m0 * 2048 + d]);
  if (dev < 1e-3f) {  // integer-decay fast path
    for (int t = 0; t < CL; ++t) {
      const int tn = (t + 1 < CL) ? t + 1 : t;
      const float dtv_n = bf2f(xzb[(m0 + tn) * 4096 + d]);
      const float xv_n = bf2f(xcb[(m0 + tn) * 2048 + d]);
      const float dtx = dtv * xv;
      sdt += dtv;
      float pw[16];
      pow_tree(__expf(-dtv), pw);
      const f32x4 B0 = *(const f32x4*)&Bsh[t][0];
      const f32x4 B1 = *(const f32x4*)&Bsh[t][4];
      const f32x4 B2 = *(const f32x4*)&Bsh[t][8];
      const f32x4 B3 = *(const f32x4*)&Bsh[t][12];
#pragma unroll
      for (int j = 0; j < 4; ++j) {
        h[j] = fmaf(pw[j], h[j], B0[j] * dtx);
        h[4 + j] = fmaf(pw[4 + j], h[4 + j], B1[j] * dtx);
        h[8 + j] = fmaf(pw[8 + j], h[8 + j], B2[j] * dtx);
        h[12 + j] = fmaf(pw[12 + j], h[12 + j], B3[j] * dtx);
      }
      dtv = dtv_n;
      xv = xv_n;
    }
  } else {
    for (int t = 0; t < CL; ++t) {
      const int tn = (t + 1 < CL) ? t + 1 : t;
      const float dtv_n = bf2f(xzb[(m0 + tn) * 4096 + d]);
      const float xv_n = bf2f(xcb[(m0 + tn) * 2048 + d]);
      const float dtx = dtv * xv;
      sdt += dtv;
#pragma unroll
      for (int n = 0; n < 16; ++n)
        h[n] = fmaf(__expf(dtv * a[n]), h[n], Bsh[t][n] * dtx);
      dtv = dtv_n;
      xv = xv_n;
    }
  }
  // coalesced: consecutive threads = consecutive d -> 256B/inst per wave
  const size_t sbase = (((size_t)b * NCH + c) * 16) * D_INNER + d;
#pragma unroll
  for (int n = 0; n < 16; ++n) S[sbase + (size_t)n * D_INNER] = h[n];
  Sdt[((size_t)b * NCH + c) * D_INNER + d] = sdt;
}

// Pass B: serial prefix over NCH chunks; S[c] becomes the INITIAL state of
// chunk c. One thread per (b,n,d) = 131072, d-fast for coalescing.
__global__ __launch_bounds__(256) void scan_passB(
    float* __restrict__ S, const float* __restrict__ Sdt,
    const void* __restrict__ A_log, const int* __restrict__ flag) {
  const int bf = *flag;
  const int idx = blockIdx.x * 256 + threadIdx.x;
  const int d = idx & (D_INNER - 1);
  const int n = (idx >> 11) & 15;
  const int b = idx >> 15;
  const float al = bf ? ld1<true>(A_log, (size_t)d * 16 + n)
                      : ld1<false>(A_log, (size_t)d * 16 + n);
  const float a = -expf(al);
  float h = 0.f;
  for (int c = 0; c < NCH; ++c) {
    const size_t base = ((size_t)b * NCH + c);
    const size_t sidx = (base * 16 + n) * D_INNER + d;
    const float s = S[sidx];
    const float sdt = Sdt[base * D_INNER + d];
    const float p = __expf(a * sdt);
    S[sidx] = h;  // init for chunk c
    h = p * h + s;
  }
}

// Pass C: replay chunk from true init state; y = (sum_n h*C + D*x)*silu(z).
__global__ __launch_bounds__(256) void scan_passC(
    const unsigned short* __restrict__ xzb,
    const unsigned short* __restrict__ xcb,
    const unsigned short* __restrict__ dbl, const void* __restrict__ A_log,
    const void* __restrict__ Dp, const float* __restrict__ S,
    const int* __restrict__ flag, unsigned short* __restrict__ ybf) {
  __shared__ float Bsh[CL][16];  // 2 KiB
  __shared__ float Csh[CL][16];  // 2 KiB
  const int bf = *flag;
  const int gid = blockIdx.x * 256 + threadIdx.x;
  const int d = gid & (D_INNER - 1);
  const int c = (gid >> 11) & (NCH - 1);
  const int b = gid >> (11 + LOG_NCH);
  const size_t m0 = (size_t)b * SEQ + c * CL;
  // cooperative fill: B and C rows, 2+2 values per thread
  {
    const int tid = threadIdx.x;
#pragma unroll
    for (int k = 0; k < (CL * 16) / 256; ++k) {
      const int idx = tid + k * 256;
      const int t = idx >> 4, n = idx & 15;
      Bsh[t][n] = bf2f(dbl[(m0 + t) * 128 + 64 + n]);
      Csh[t][n] = bf2f(dbl[(m0 + t) * 128 + 80 + n]);
    }
  }
  float a[16], dev;
  load_a(A_log, bf, d, a, dev);
  const float Dv = bf ? ld1<true>(Dp, d) : ld1<false>(Dp, d);
  float h[16];
  const size_t sbase = (((size_t)b * NCH + c) * 16) * D_INNER + d;
#pragma unroll
  for (int n = 0; n < 16; ++n) h[n] = S[sbase + (size_t)n * D_INNER];
  __syncthreads();
  const bool trick = dev < 1e-3f;
  // R13: depth-1 register prefetch (dtv/xv/zv)
  float dtv = bf2f(xzb[m0 * 4096 + d]);
  float xv = bf2f(xcb[m0 * 2048 + d]);
  float zv = bf2f(xzb[m0 * 4096 + 2048 + d]);
  for (int t = 0; t < CL; ++t) {
    const int tn = (t + 1 < CL) ? t + 1 : t;
    const float dtv_n = bf2f(xzb[(m0 + tn) * 4096 + d]);
    const float xv_n = bf2f(xcb[(m0 + tn) * 2048 + d]);
    const float zv_n = bf2f(xzb[(m0 + tn) * 4096 + 2048 + d]);
    const size_t m = m0 + t;
    const float dtx = dtv * xv;
    float y = 0.f;
    if (trick) {
      float pw[16];
      pow_tree(__expf(-dtv), pw);
      const f32x4 B0 = *(const f32x4*)&Bsh[t][0];
      const f32x4 B1 = *(const f32x4*)&Bsh[t][4];
      const f32x4 B2 = *(const f32x4*)&Bsh[t][8];
      const f32x4 B3 = *(const f32x4*)&Bsh[t][12];
      const f32x4 C0 = *(const f32x4*)&Csh[t][0];
      const f32x4 C1 = *(const f32x4*)&Csh[t][4];
      const f32x4 C2 = *(const f32x4*)&Csh[t][8];
      const f32x4 C3 = *(const f32x4*)&Csh[t][12];
#pragma unroll
      for (int j = 0; j < 4; ++j) {
        h[j] = fmaf(pw[j], h[j], B0[j] * dtx);
        y = fmaf(h[j], C0[j], y);
        h[4 + j] = fmaf(pw[4 + j], h[4 + j], B1[j] * dtx);
        y = fmaf(h[4 + j], C1[j], y);
        h[8 + j] = fmaf(pw[8 + j], h[8 + j], B2[j] * dtx);
        y = fmaf(h[8 + j], C2[j], y);
        h[12 + j] = fmaf(pw[12 + j], h[12 + j], B3[j] * dtx);
        y = fmaf(h[12 + j], C3[j], y);
      }
    } else {
#pragma unroll
      for (int n = 0; n < 16; ++n) {
        h[n] = fmaf(__expf(dtv * a[n]), h[n], Bsh[t][n] * dtx);
        y = fmaf(h[n], Csh[t][n], y);
      }
    }
    const float yv = y + Dv * xv;
    ybf[m * 2048 + d] = f2bf(yv * (zv / (1.f + __expf(-zv))));
    dtv = dtv_n;
    xv = xv_n;
    zv = zv_n;
  }
}

// ---------------------------------------------------------------------------
extern "C" void kernel_launch(void* const* d_in, const int* in_sizes, int n_in,
                              void* d_out, int out_size, void* d_ws,
                              size_t ws_size, hipStream_t stream) {
  const void* x = d_in[0];
  const void* in_proj_w = d_in[1];
  const void* conv_w = d_in[2];
  const void* conv_b = d_in[3];
  const void* x_proj_w = d_in[4];
  const void* dt_proj_w = d_in[5];
  const void* dt_proj_b = d_in[6];
  const void* A_log = d_in[7];
  const void* D_param = d_in[8];
  const void* out_proj_w = d_in[9];

  // ws layout:
  // flag 256B | xzb 64MB | xcb 32MB (pre-conv hosts x_bf+ipw_bf) | dbl 2MB |
  // ybf 32MB | S 33.5MB (NCH=64; aliases k3part 16.8MB pre-scan) | Sdt 2MB |
  // opw 4MB | xpw_pad 512KB | dtw 256KB
  char* wsb = (char*)d_ws;
  int* flag = (int*)wsb;
  unsigned short* xzb = (unsigned short*)(wsb + 256);
  unsigned short* xcb = xzb + (size_t)ML * 4096;
  unsigned short* dbl = xcb + (size_t)ML * 2048;
  unsigned short* ybf = dbl + (size_t)ML * 128;
  float* S = (float*)(ybf + (size_t)ML * 2048);
  float* Sdt = S + (size_t)BATCH * NCH * D_INNER * 16;
  unsigned short* opw_bf =
      (unsigned short*)(Sdt + (size_t)BATCH * NCH * D_INNER);
  unsigned short* xpw_pad = opw_bf + (size_t)1024 * 2048;
  unsigned short* dtw_bf = xpw_pad + (size_t)128 * 2048;
  unsigned short* x_bf = xcb;                        // dead after K1
  unsigned short* ipw_bf = xcb + (size_t)ML * 1024;  // dead after K1
  float* k3part = S;  // 4 x (ML x 128) f32 = 16.78 MB; dead before scans

  // fused conversions + inline dtype detection (one dispatch)
  cvt_all_kernel<<<CVT_E4 / 1024, 256, 0, stream>>>(
      x, in_proj_w, out_proj_w, dt_proj_w, x_proj_w, x_bf, ipw_bf, opw_bf,
      dtw_bf, xpw_pad, flag);
  // K1: xz = x @ in_proj_w^T (M=8192,N=4096,K=1024) -> xzb bf16
  gemm256_k1<<<dim3(512), 512, 0, stream>>>(x_bf, ipw_bf, xzb);
  // K2: causal depthwise conv + SiLU -> xcb bf16 (x_bf/ipw_bf now dead)
  conv_silu_kernel<<<(ML * D_INNER) / 1024, 256, 0, stream>>>(
      xzb, conv_w, conv_b, xcb, flag);
  // K3: dbl = xc @ x_proj_w^T (M=8192, N=128(pad), K=2048), split-K x4 ->
  // f32 partials in S region, then reduce+bf16.
  {
    dim3 g(1, ML / 128, 4);
    gemm_mfma<3, 3><<<g, 256, 0, stream>>>(xcb, 2048, xpw_pad, 2048, k3part,
                                           128, 512, nullptr, flag);
  }
  reduceK3_kernel<<<(ML * 128) / 1024, 256, 0, stream>>>(k3part, dbl);
  // K4: dt = softplus(dbl[:,:64] @ dt_proj_w^T + b) -> xzb x-half (ldc=4096)
  dt_gemm_kernel<<<dim3(16, 64), 256, 0, stream>>>(dbl, dtw_bf, xzb,
                                                   dt_proj_b, flag);
  // K5: chunked scan, NCH=64, LDS-staged f32 B/C + reg prefetch (R13)
  scan_passA<<<(BATCH * NCH * D_INNER) / 256, 256, 0, stream>>>(
      xzb, xcb, dbl, A_log, flag, S, Sdt);
  scan_passB<<<(BATCH * D_INNER * 16) / 256, 256, 0, stream>>>(S, Sdt, A_log,
                                                               flag);
  scan_passC<<<(BATCH * NCH * D_INNER) / 256, 256, 0, stream>>>(
      xzb, xcb, dbl, A_log, D_param, S, flag, ybf);
  // K6: out = y @ out_proj_w^T (M=8192,N=1024,K=2048), out dtype per flag
  gemm256x128_k6<<<dim3(256), 512, 0, stream>>>(ybf, opw_bf, d_out, flag);
}